// Round 1
// baseline (377.285 us; speedup 1.0000x reference)
//
#include <hip/hip_runtime.h>

#define DM 1024
#define NH 16
#define HD 64
#define FD 16
#define NF 153
#define FPAD 160
#define WIN 64
#define TSEQ 2048
#define ROWS 4096
#define NC 8
#define SCH 256

typedef unsigned short u16;
typedef __attribute__((ext_vector_type(8))) short bf16x8;
typedef __attribute__((ext_vector_type(8))) unsigned short u16x8;
typedef __attribute__((ext_vector_type(4))) unsigned short u16x4;
typedef __attribute__((ext_vector_type(4))) float f32x4;

static __device__ __forceinline__ float bf2f(u16 u){
  unsigned v = ((unsigned)u) << 16;
  return __builtin_bit_cast(float, v);
}
static __device__ __forceinline__ u16 f2bf(float f){
  unsigned u = __builtin_bit_cast(unsigned, f);
  u += 0x7FFFu + ((u >> 16) & 1u);
  return (u16)(u >> 16);
}

// ---------------- RMSNorm + cast to bf16 ----------------
__global__ __launch_bounds__(256) void k_rmsnorm(const float* __restrict__ x,
    const float* __restrict__ w, u16* __restrict__ out){
  int row = blockIdx.x;
  int tid = threadIdx.x;
  const float4* xr = (const float4*)(x + (size_t)row*DM);
  float4 a = xr[tid];
  float ss = a.x*a.x + a.y*a.y + a.z*a.z + a.w*a.w;
  #pragma unroll
  for (int m=1;m<64;m<<=1) ss += __shfl_xor(ss, m);
  __shared__ float red[4];
  if ((tid&63)==0) red[tid>>6] = ss;
  __syncthreads();
  float tot = red[0]+red[1]+red[2]+red[3];
  float rs = rsqrtf(tot*(1.0f/DM) + 1e-6f);
  float4 wv = ((const float4*)w)[tid];
  u16x4 o;
  o[0] = f2bf(a.x*rs*wv.x);
  o[1] = f2bf(a.y*rs*wv.y);
  o[2] = f2bf(a.z*rs*wv.z);
  o[3] = f2bf(a.w*rs*wv.w);
  ((u16x4*)(out + (size_t)row*DM))[tid] = o;
}

// ---------------- f32 -> bf16 cast ----------------
__global__ __launch_bounds__(256) void k_cast_bf16(const float* __restrict__ in,
    u16* __restrict__ out, int n4){
  int i = blockIdx.x*256 + threadIdx.x;
  if (i >= n4) return;
  float4 a = ((const float4*)in)[i];
  u16x4 o;
  o[0]=f2bf(a.x); o[1]=f2bf(a.y); o[2]=f2bf(a.z); o[3]=f2bf(a.w);
  ((u16x4*)out)[i] = o;
}

// ---------------- transpose + cast: in (K x N) f32 -> out (N x K) bf16 ----------------
__global__ __launch_bounds__(256) void k_transpose(const float* __restrict__ in,
    u16* __restrict__ out, int K, int N){
  __shared__ float t[32][33];
  int n0 = blockIdx.x*32, k0 = blockIdx.y*32;
  int tx = threadIdx.x & 31, ty = threadIdx.x >> 5;
  #pragma unroll
  for (int i=0;i<4;i++) t[ty + i*8][tx] = in[(size_t)(k0 + ty + i*8)*N + n0 + tx];
  __syncthreads();
  #pragma unroll
  for (int i=0;i<4;i++) out[(size_t)(n0 + ty + i*8)*K + k0 + tx] = f2bf(t[tx][ty + i*8]);
}

// ---------------- main GEMM: C(MxN) = A(MxK) * Bt(NxK)^T  (bf16 in, f32 acc) ----------------
template<int EPI>
__global__ __launch_bounds__(256) void k_gemm(const u16* __restrict__ A, const u16* __restrict__ Bt,
    u16* __restrict__ C, float* __restrict__ Cf, const float* __restrict__ resid,
    int M, int N, int K){
  const int LS = 72;  // padded LDS row stride (bf16 elems): 144B -> 4-bank rotate per row
  __shared__ u16 As[128*LS];
  __shared__ u16 Bs[128*LS];
  int row0 = blockIdx.x*128, col0 = blockIdx.y*128;
  int tid = threadIdx.x, lane = tid&63, wid = tid>>6;
  int wr = wid>>1, wc = wid&1;
  f32x4 acc[4][4] = {};
  for (int k0=0;k0<K;k0+=64){
    __syncthreads();
    #pragma unroll
    for (int j=0;j<4;j++){
      int c = tid + j*256;
      int r = c>>3, c8 = c&7;
      *(bf16x8*)(As + r*LS + c8*8) = *(const bf16x8*)(A  + (size_t)(row0+r)*K + k0 + c8*8);
      *(bf16x8*)(Bs + r*LS + c8*8) = *(const bf16x8*)(Bt + (size_t)(col0+r)*K + k0 + c8*8);
    }
    __syncthreads();
    #pragma unroll
    for (int kk=0;kk<64;kk+=32){
      int lk = kk + ((lane>>4)<<3);
      bf16x8 af[4], bfm[4];
      #pragma unroll
      for (int m=0;m<4;m++) af[m]  = *(const bf16x8*)(As + (wr*64 + m*16 + (lane&15))*LS + lk);
      #pragma unroll
      for (int n=0;n<4;n++) bfm[n] = *(const bf16x8*)(Bs + (wc*64 + n*16 + (lane&15))*LS + lk);
      #pragma unroll
      for (int m=0;m<4;m++)
        #pragma unroll
        for (int n=0;n<4;n++)
          acc[m][n] = __builtin_amdgcn_mfma_f32_16x16x32_bf16(af[m], bfm[n], acc[m][n], 0,0,0);
    }
  }
  int rl = (lane>>4)<<2;
  #pragma unroll
  for (int m=0;m<4;m++){
    #pragma unroll
    for (int n=0;n<4;n++){
      int gc = col0 + wc*64 + n*16 + (lane&15);
      #pragma unroll
      for (int r=0;r<4;r++){
        size_t gi = (size_t)(row0 + wr*64 + m*16 + rl + r)*N + gc;
        if constexpr (EPI) Cf[gi] = acc[m][n][r] + resid[gi];
        else               C[gi]  = f2bf(acc[m][n][r]);
      }
    }
  }
}

// ---------------- Taylor feature map: phi = [1, xf, triu(xf xf^T * scale)] ----------------
__global__ __launch_bounds__(256) void k_feature(const u16* __restrict__ X, int ldx,
    const float* __restrict__ W, u16* __restrict__ phi){
  __shared__ float Ws[HD*FD];
  int tid = threadIdx.x;
  for (int i=tid;i<HD*FD;i+=256) Ws[i] = W[i];
  __syncthreads();
  int h = tid & 15;
  size_t row = (size_t)blockIdx.x*16 + (tid>>4);
  const u16* xp = X + row*ldx + h*HD;
  float xv[HD];
  #pragma unroll
  for (int i=0;i<8;i++){
    u16x8 v = *(const u16x8*)(xp + i*8);
    #pragma unroll
    for (int j=0;j<8;j++) xv[i*8+j] = bf2f(v[j]);
  }
  float f[FD];
  #pragma unroll
  for (int j=0;j<FD;j++) f[j] = 0.f;
  for (int d=0; d<HD; d++){
    float xd = xv[d];
    #pragma unroll
    for (int j=0;j<FD;j++) f[j] += xd * Ws[d*FD + j];
  }
  u16 buf[FPAD];
  buf[0] = 0x3F80;  // bf16(1.0)
  #pragma unroll
  for (int i=0;i<FD;i++) buf[1+i] = f2bf(f[i]);
  int idx = 1+FD;
  #pragma unroll
  for (int i=0;i<FD;i++){
    #pragma unroll
    for (int j=i;j<FD;j++){
      float sc = (i==j) ? 0.5f : 0.70710678118654752f;
      buf[idx++] = f2bf(f[i]*f[j]*sc);
    }
  }
  #pragma unroll
  for (int z=NF;z<FPAD;z++) buf[z] = 0;
  u16x8* ov = (u16x8*)(phi + (row*NH + h)*FPAD);
  #pragma unroll
  for (int i2=0;i2<FPAD/8;i2++){
    u16x8 t;
    #pragma unroll
    for (int j=0;j<8;j++) t[j] = buf[i2*8+j];
    ov[i2] = t;
  }
}

// ---------------- kv_state split-K partials: part[c][bh][d][f] = sum_s kphi*v ----------------
__global__ __launch_bounds__(256) void k_kvpart(const u16* __restrict__ kphi,
    const u16* __restrict__ kvmat, float* __restrict__ part, float* __restrict__ ksP){
  int bh = blockIdx.x, b = bh>>4, h = bh&15;
  int c = blockIdx.y;
  int tid = threadIdx.x;
  int d = tid&63, fg = tid>>6;
  __shared__ float kp[8][FPAD];
  __shared__ float vv[8][64];
  float acc[40];
  #pragma unroll
  for (int j=0;j<40;j++) acc[j]=0.f;
  int s0 = c*SCH;
  for (int ss=0;ss<SCH;ss+=8){
    __syncthreads();
    for (int i=tid;i<8*FPAD;i+=256){
      int si = i/FPAD, ff = i - si*FPAD;
      kp[si][ff] = bf2f(kphi[((size_t)(b*TSEQ + s0+ss+si)*NH + h)*FPAD + ff]);
    }
    for (int i=tid;i<512;i+=256){
      int si = i>>6, dd = i&63;
      vv[si][dd] = bf2f(kvmat[(size_t)(b*TSEQ + s0+ss+si)*2048 + 1024 + h*64 + dd]);
    }
    __syncthreads();
    #pragma unroll
    for (int si=0;si<8;si++){
      float vd = vv[si][d];
      const float* kpr = &kp[si][fg*40];
      #pragma unroll
      for (int j=0;j<40;j++) acc[j] += vd * kpr[j];
    }
  }
  float* pp = part + (((size_t)c*32 + bh)*64 + d)*FPAD + fg*40;
  #pragma unroll
  for (int j=0;j<40;j++) pp[j] = acc[j];
  if (tid < FPAD){
    float s = 0.f;
    for (int ss=0;ss<SCH;ss++)
      s += bf2f(kphi[((size_t)(b*TSEQ + s0+ss)*NH + h)*FPAD + tid]);
    ksP[((size_t)c*32 + bh)*FPAD + tid] = s;
  }
}

// ---------------- assemble kvsT: (bh, 80, FPAD): rows 0..63 = kv_state^T, 64 = k_state, 65.. = 0
__global__ __launch_bounds__(256) void k_kvassemble(const float* __restrict__ part,
    const float* __restrict__ ksP, u16* __restrict__ kvsT){
  int bh = blockIdx.x, tid = threadIdx.x;
  for (int e=tid; e<80*FPAD; e+=256){
    int dd = e/FPAD, ff = e - dd*FPAD;
    float s = 0.f;
    if (dd < 64){
      #pragma unroll
      for (int cc=0;cc<NC;cc++) s += part[(((size_t)cc*32+bh)*64+dd)*FPAD + ff];
    } else if (dd == 64){
      #pragma unroll
      for (int cc=0;cc<NC;cc++) s += ksP[((size_t)cc*32+bh)*FPAD + ff];
    }
    kvsT[((size_t)bh*80 + dd)*FPAD + ff] = f2bf(s);
  }
}

// ---------------- linear attention output: qphi @ [kv_state | k_state], normalize ----------------
__global__ __launch_bounds__(256) void k_linattn(const u16* __restrict__ qphi,
    const u16* __restrict__ kvsT, u16* __restrict__ comb){
  const int LS = 168;
  __shared__ u16 As[64*LS];
  __shared__ u16 Bs[80*LS];
  int bh = blockIdx.x, b = bh>>4, h = bh&15;
  int t0 = blockIdx.y*64;
  int tid = threadIdx.x, lane = tid&63, wid = tid>>6;
  for (int i=tid*8; i<64*FPAD; i+=2048){
    int r = i/FPAD, ff = i - r*FPAD;
    *(bf16x8*)(As + r*LS + ff) = *(const bf16x8*)(qphi + ((size_t)(b*TSEQ + t0 + r)*NH + h)*FPAD + ff);
  }
  for (int i=tid*8; i<80*FPAD; i+=2048){
    int r = i/FPAD, ff = i - r*FPAD;
    *(bf16x8*)(Bs + r*LS + ff) = *(const bf16x8*)(kvsT + (size_t)bh*80*FPAD + i);
  }
  __syncthreads();
  f32x4 acc[5] = {};
  #pragma unroll
  for (int ks=0;ks<5;ks++){
    int lk = ks*32 + ((lane>>4)<<3);
    bf16x8 a = *(const bf16x8*)(As + (wid*16 + (lane&15))*LS + lk);
    #pragma unroll
    for (int n=0;n<5;n++){
      bf16x8 bb = *(const bf16x8*)(Bs + (n*16 + (lane&15))*LS + lk);
      acc[n] = __builtin_amdgcn_mfma_f32_16x16x32_bf16(a, bb, acc[n], 0,0,0);
    }
  }
  int rl = (lane>>4)<<2;
  #pragma unroll
  for (int r=0;r<4;r++){
    float nrm = __shfl(acc[4][r], lane & 48) + 1e-6f;  // col 64 lives in lane (lane&48)
    float inv = 1.0f / nrm;
    int t = t0 + wid*16 + rl + r;
    #pragma unroll
    for (int n=0;n<4;n++){
      comb[(size_t)(b*TSEQ + t)*2048 + h*64 + n*16 + (lane&15)] = f2bf(acc[n][r]*inv);
    }
  }
}

// ---------------- sliding-window attention (window = 65 incl. self) ----------------
__global__ __launch_bounds__(256) void k_window(const u16* __restrict__ q,
    const u16* __restrict__ kvwin, u16* __restrict__ comb){
  const int LQ = 72, LV = 136;
  __shared__ u16 q_s [64*LQ];
  __shared__ u16 k_s [128*LQ];
  __shared__ u16 vT_s[64*LV];
  __shared__ u16 p_s [64*LV];
  int bh = blockIdx.x, b = bh>>4, h = bh&15;
  int t0 = blockIdx.y*64;
  int tid = threadIdx.x, lane = tid&63, wid = tid>>6;
  int j0 = t0 - 64;
  bf16x8 zv = {0,0,0,0,0,0,0,0};
  for (int cc=tid; cc<512; cc+=256){
    int r = cc>>3, c8 = cc&7;
    *(bf16x8*)(q_s + r*LQ + c8*8) =
      *(const bf16x8*)(q + (size_t)(b*TSEQ + t0 + r)*DM + h*HD + c8*8);
  }
  for (int cc=tid; cc<1024; cc+=256){
    int r = cc>>3, c8 = cc&7;
    int j = j0 + r;
    bf16x8 kv8 = (j>=0) ? *(const bf16x8*)(kvwin + (size_t)(b*TSEQ + j)*2048 + h*HD + c8*8) : zv;
    *(bf16x8*)(k_s + r*LQ + c8*8) = kv8;
    bf16x8 vv8 = (j>=0) ? *(const bf16x8*)(kvwin + (size_t)(b*TSEQ + j)*2048 + 1024 + h*HD + c8*8) : zv;
    #pragma unroll
    for (int e=0;e<8;e++) vT_s[(c8*8+e)*LV + r] = (u16)vv8[e];
  }
  __syncthreads();
  f32x4 sa[8] = {};
  #pragma unroll
  for (int kk=0;kk<64;kk+=32){
    int lk = kk + ((lane>>4)<<3);
    bf16x8 a = *(const bf16x8*)(q_s + (wid*16 + (lane&15))*LQ + lk);
    #pragma unroll
    for (int n=0;n<8;n++){
      bf16x8 bb = *(const bf16x8*)(k_s + (n*16 + (lane&15))*LQ + lk);
      sa[n] = __builtin_amdgcn_mfma_f32_16x16x32_bf16(a, bb, sa[n], 0,0,0);
    }
  }
  int rl = (lane>>4)<<2;
  float pr[8][4];
  #pragma unroll
  for (int r=0;r<4;r++){
    int ig = t0 + wid*16 + rl + r;
    float mx = -1e30f;
    float sv[8];
    #pragma unroll
    for (int n=0;n<8;n++){
      int jg = j0 + n*16 + (lane&15);
      float s = sa[n][r]*0.125f;
      bool ok = (jg>=0) && (jg<=ig) && (jg>=ig-WIN);
      s = ok ? s : -1e30f;
      sv[n]=s; mx = fmaxf(mx, s);
    }
    #pragma unroll
    for (int m=1;m<16;m<<=1) mx = fmaxf(mx, __shfl_xor(mx, m));
    float sum = 0.f;
    #pragma unroll
    for (int n=0;n<8;n++){ float e = __expf(sv[n]-mx); sv[n]=e; sum += e; }
    #pragma unroll
    for (int m=1;m<16;m<<=1) sum += __shfl_xor(sum, m);
    float inv = 1.0f/sum;
    #pragma unroll
    for (int n=0;n<8;n++) pr[n][r] = sv[n]*inv;
  }
  #pragma unroll
  for (int n=0;n<8;n++)
    #pragma unroll
    for (int r=0;r<4;r++)
      p_s[(wid*16 + rl + r)*LV + n*16 + (lane&15)] = f2bf(pr[n][r]);
  __syncthreads();
  f32x4 oa[4] = {};
  #pragma unroll
  for (int ks=0;ks<4;ks++){
    int lk = ks*32 + ((lane>>4)<<3);
    bf16x8 a = *(const bf16x8*)(p_s + (wid*16 + (lane&15))*LV + lk);
    #pragma unroll
    for (int n=0;n<4;n++){
      bf16x8 bb = *(const bf16x8*)(vT_s + (n*16 + (lane&15))*LV + lk);
      oa[n] = __builtin_amdgcn_mfma_f32_16x16x32_bf16(a, bb, oa[n], 0,0,0);
    }
  }
  #pragma unroll
  for (int n=0;n<4;n++)
    #pragma unroll
    for (int r=0;r<4;r++)
      comb[(size_t)(b*TSEQ + t0 + wid*16 + rl + r)*2048 + 1024 + h*HD + n*16 + (lane&15)]
        = f2bf(oa[n][r]);
}

extern "C" void kernel_launch(void* const* d_in, const int* in_sizes, int n_in,
                              void* d_out, int out_size, void* d_ws, size_t ws_size,
                              hipStream_t stream){
  (void)in_sizes; (void)n_in; (void)out_size; (void)ws_size;
  const float* x    = (const float*)d_in[0];
  const float* enc  = (const float*)d_in[1];
  const float* nw   = (const float*)d_in[2];
  const float* Wq   = (const float*)d_in[3];
  const float* Wkv  = (const float*)d_in[4];
  const float* Wqf  = (const float*)d_in[5];
  const float* Wkf  = (const float*)d_in[6];
  const float* Wwin = (const float*)d_in[7];
  const float* Wout = (const float*)d_in[8];
  float* out = (float*)d_out;

  char* p = (char*)d_ws;
  auto alloc = [&](size_t bytes)->char*{
    char* r = p; p += (bytes + 255) & ~(size_t)255; return r;
  };
  u16*   xn    = (u16*)  alloc((size_t)ROWS*DM*2);
  u16*   encb  = (u16*)  alloc((size_t)ROWS*DM*2);
  u16*   WqT   = (u16*)  alloc((size_t)DM*DM*2);
  u16*   WkvT  = (u16*)  alloc((size_t)2048*DM*2);
  u16*   WwinT = (u16*)  alloc((size_t)2048*DM*2);
  u16*   WoutT = (u16*)  alloc((size_t)DM*2048*2);
  u16*   qb    = (u16*)  alloc((size_t)ROWS*DM*2);
  u16*   kvb   = (u16*)  alloc((size_t)ROWS*2048*2);
  u16*   kvwb  = (u16*)  alloc((size_t)ROWS*2048*2);
  u16*   qphi  = (u16*)  alloc((size_t)ROWS*NH*FPAD*2);
  u16*   kphi  = (u16*)  alloc((size_t)ROWS*NH*FPAD*2);
  float* part  = (float*)alloc((size_t)NC*32*64*FPAD*4);
  float* ksP   = (float*)alloc((size_t)NC*32*FPAD*4);
  u16*   kvsT  = (u16*)  alloc((size_t)32*80*FPAD*2);
  u16*   comb  = (u16*)  alloc((size_t)ROWS*2048*2);

  k_rmsnorm<<<ROWS, 256, 0, stream>>>(x, nw, xn);
  k_cast_bf16<<<(ROWS*DM/4 + 255)/256, 256, 0, stream>>>(enc, encb, ROWS*DM/4);
  k_transpose<<<dim3(DM/32,   DM/32),   256, 0, stream>>>(Wq,   WqT,   DM,   DM);
  k_transpose<<<dim3(2048/32, DM/32),   256, 0, stream>>>(Wkv,  WkvT,  DM,   2048);
  k_transpose<<<dim3(2048/32, DM/32),   256, 0, stream>>>(Wwin, WwinT, DM,   2048);
  k_transpose<<<dim3(DM/32,   2048/32), 256, 0, stream>>>(Wout, WoutT, 2048, DM);

  k_gemm<0><<<dim3(ROWS/128, DM/128),   256, 0, stream>>>(xn,   WqT,   qb,   nullptr, nullptr, ROWS, DM,   DM);
  k_gemm<0><<<dim3(ROWS/128, 2048/128), 256, 0, stream>>>(encb, WkvT,  kvb,  nullptr, nullptr, ROWS, 2048, DM);
  k_gemm<0><<<dim3(ROWS/128, 2048/128), 256, 0, stream>>>(xn,   WwinT, kvwb, nullptr, nullptr, ROWS, 2048, DM);

  k_feature<<<ROWS/16, 256, 0, stream>>>(qb,  DM,   Wqf, qphi);
  k_feature<<<ROWS/16, 256, 0, stream>>>(kvb, 2048, Wkf, kphi);

  k_kvpart<<<dim3(32, NC), 256, 0, stream>>>(kphi, kvb, part, ksP);
  k_kvassemble<<<32, 256, 0, stream>>>(part, ksP, kvsT);

  k_linattn<<<dim3(32, TSEQ/64), 256, 0, stream>>>(qphi, kvsT, comb);
  k_window <<<dim3(32, TSEQ/64), 256, 0, stream>>>(qb, kvwb, comb);

  k_gemm<1><<<dim3(ROWS/128, DM/128), 256, 0, stream>>>(comb, WoutT, nullptr, out, x, ROWS, DM, 2048);
}

// Round 2
// 269.044 us; speedup vs baseline: 1.4023x; 1.4023x over previous
//
#include <hip/hip_runtime.h>

#define DM 1024
#define NH 16
#define HD 64
#define FD 16
#define NF 153
#define FPAD 160
#define WIN 64
#define TSEQ 2048
#define ROWS 4096
#define KSPLIT 16

typedef unsigned short u16;
typedef __attribute__((ext_vector_type(8))) short bf16x8;
typedef __attribute__((ext_vector_type(8))) unsigned short u16x8;
typedef __attribute__((ext_vector_type(4))) unsigned short u16x4;
typedef __attribute__((ext_vector_type(4))) float f32x4;

static __device__ __forceinline__ float bf2f(u16 u){
  unsigned v = ((unsigned)u) << 16;
  return __builtin_bit_cast(float, v);
}
static __device__ __forceinline__ u16 f2bf(float f){
  unsigned u = __builtin_bit_cast(unsigned, f);
  u += 0x7FFFu + ((u >> 16) & 1u);
  return (u16)(u >> 16);
}

// ---------------- RMSNorm + cast to bf16 ----------------
__global__ __launch_bounds__(256) void k_rmsnorm(const float* __restrict__ x,
    const float* __restrict__ w, u16* __restrict__ out){
  int row = blockIdx.x;
  int tid = threadIdx.x;
  const float4* xr = (const float4*)(x + (size_t)row*DM);
  float4 a = xr[tid];
  float ss = a.x*a.x + a.y*a.y + a.z*a.z + a.w*a.w;
  #pragma unroll
  for (int m=1;m<64;m<<=1) ss += __shfl_xor(ss, m);
  __shared__ float red[4];
  if ((tid&63)==0) red[tid>>6] = ss;
  __syncthreads();
  float tot = red[0]+red[1]+red[2]+red[3];
  float rs = rsqrtf(tot*(1.0f/DM) + 1e-6f);
  float4 wv = ((const float4*)w)[tid];
  u16x4 o;
  o[0] = f2bf(a.x*rs*wv.x);
  o[1] = f2bf(a.y*rs*wv.y);
  o[2] = f2bf(a.z*rs*wv.z);
  o[3] = f2bf(a.w*rs*wv.w);
  ((u16x4*)(out + (size_t)row*DM))[tid] = o;
}

// ---------------- f32 -> bf16 cast ----------------
__global__ __launch_bounds__(256) void k_cast_bf16(const float* __restrict__ in,
    u16* __restrict__ out, int n4){
  int i = blockIdx.x*256 + threadIdx.x;
  if (i >= n4) return;
  float4 a = ((const float4*)in)[i];
  u16x4 o;
  o[0]=f2bf(a.x); o[1]=f2bf(a.y); o[2]=f2bf(a.z); o[3]=f2bf(a.w);
  ((u16x4*)out)[i] = o;
}

// ---------------- transpose + cast: in (K x N) f32 -> out (N x K) bf16 ----------------
__global__ __launch_bounds__(256) void k_transpose(const float* __restrict__ in,
    u16* __restrict__ out, int K, int N){
  __shared__ float t[32][33];
  int n0 = blockIdx.x*32, k0 = blockIdx.y*32;
  int tx = threadIdx.x & 31, ty = threadIdx.x >> 5;
  #pragma unroll
  for (int i=0;i<4;i++) t[ty + i*8][tx] = in[(size_t)(k0 + ty + i*8)*N + n0 + tx];
  __syncthreads();
  #pragma unroll
  for (int i=0;i<4;i++) out[(size_t)(n0 + ty + i*8)*K + k0 + tx] = f2bf(t[tx][ty + i*8]);
}

// ---------------- main GEMM: C(MxN) = A(MxK) * Bt(NxK)^T  (bf16 in, f32 acc) ----------------
template<int EPI>
__global__ __launch_bounds__(256) void k_gemm(const u16* __restrict__ A, const u16* __restrict__ Bt,
    u16* __restrict__ C, float* __restrict__ Cf, const float* __restrict__ resid,
    int M, int N, int K){
  const int LS = 72;  // 144B row stride: 16-lane frag reads land 2/bank (free)
  __shared__ u16 As[128*LS];
  __shared__ u16 Bs[128*LS];
  int row0 = blockIdx.x*128, col0 = blockIdx.y*128;
  int tid = threadIdx.x, lane = tid&63, wid = tid>>6;
  int wr = wid>>1, wc = wid&1;
  f32x4 acc[4][4] = {};
  for (int k0=0;k0<K;k0+=64){
    __syncthreads();
    #pragma unroll
    for (int j=0;j<4;j++){
      int c = tid + j*256;
      int r = c>>3, c8 = c&7;
      *(bf16x8*)(As + r*LS + c8*8) = *(const bf16x8*)(A  + (size_t)(row0+r)*K + k0 + c8*8);
      *(bf16x8*)(Bs + r*LS + c8*8) = *(const bf16x8*)(Bt + (size_t)(col0+r)*K + k0 + c8*8);
    }
    __syncthreads();
    #pragma unroll
    for (int kk=0;kk<64;kk+=32){
      int lk = kk + ((lane>>4)<<3);
      bf16x8 af[4], bfm[4];
      #pragma unroll
      for (int m=0;m<4;m++) af[m]  = *(const bf16x8*)(As + (wr*64 + m*16 + (lane&15))*LS + lk);
      #pragma unroll
      for (int n=0;n<4;n++) bfm[n] = *(const bf16x8*)(Bs + (wc*64 + n*16 + (lane&15))*LS + lk);
      #pragma unroll
      for (int m=0;m<4;m++)
        #pragma unroll
        for (int n=0;n<4;n++)
          acc[m][n] = __builtin_amdgcn_mfma_f32_16x16x32_bf16(af[m], bfm[n], acc[m][n], 0,0,0);
    }
  }
  int rl = (lane>>4)<<2;
  #pragma unroll
  for (int m=0;m<4;m++){
    #pragma unroll
    for (int n=0;n<4;n++){
      int gc = col0 + wc*64 + n*16 + (lane&15);
      #pragma unroll
      for (int r=0;r<4;r++){
        size_t gi = (size_t)(row0 + wr*64 + m*16 + rl + r)*N + gc;
        if constexpr (EPI) Cf[gi] = acc[m][n][r] + resid[gi];
        else               C[gi]  = f2bf(acc[m][n][r]);
      }
    }
  }
}

// ---------------- Taylor feature map (streamed, fully static indexing) ----------------
__global__ __launch_bounds__(256) void k_feature(const u16* __restrict__ X, int ldx,
    const float* __restrict__ W, u16* __restrict__ phi){
  __shared__ float Ws[HD*FD];
  int tid = threadIdx.x;
  for (int i=tid;i<HD*FD;i+=256) Ws[i] = W[i];
  __syncthreads();
  int id = blockIdx.x*256 + tid;
  int h = id & 15;
  size_t row = (size_t)(id >> 4);
  const u16* xp = X + row*ldx + h*HD;
  float f[FD];
  #pragma unroll
  for (int q=0;q<FD;q++) f[q] = 0.f;
  #pragma unroll
  for (int i=0;i<8;i++){
    u16x8 v = *(const u16x8*)(xp + i*8);
    #pragma unroll
    for (int j=0;j<8;j++){
      float xd = bf2f(v[j]);
      const float* wr = &Ws[(i*8+j)*FD];
      #pragma unroll
      for (int q=0;q<FD;q++) f[q] += xd * wr[q];
    }
  }
  u16 buf[FPAD];
  buf[0] = 0x3F80;  // bf16(1.0)
  #pragma unroll
  for (int i=0;i<FD;i++) buf[1+i] = f2bf(f[i]);
  int idx = 1+FD;
  #pragma unroll
  for (int i=0;i<FD;i++){
    #pragma unroll
    for (int j=i;j<FD;j++){
      float sc = (i==j) ? 0.5f : 0.70710678118654752f;
      buf[idx++] = f2bf(f[i]*f[j]*sc);
    }
  }
  #pragma unroll
  for (int z=NF;z<FPAD;z++) buf[z] = 0;
  u16* op = phi + (size_t)id*FPAD;
  #pragma unroll
  for (int c=0;c<FPAD/8;c++){
    u16x8 t;
    #pragma unroll
    for (int j=0;j<8;j++) t[j] = buf[c*8+j];
    *(u16x8*)(op + c*8) = t;
  }
}

// ---------------- kv_state via MFMA, split-K ----------------
// part[ks][bh][d 0..79][f 0..159] = sum_{s in chunk} vT[d][s] * phiT[f][s]
// row d=64 of vT is ones -> k_state; rows 65..79 zero.
__global__ __launch_bounds__(320) void k_kvstate(const u16* __restrict__ kphi,
    const u16* __restrict__ kvb, float* __restrict__ part){
  const int P = 76;  // pad: frag b64 reads 2-way; scatter writes ~4-way
  __shared__ u16 ph[160*P];
  __shared__ u16 vt[80*P];
  int bh = blockIdx.x, b = bh>>4, h = bh&15;
  int ks = blockIdx.y;
  int tid = threadIdx.x, lane = tid&63, w = tid>>6;
  // constant rows of vt: d=64 -> ones, 65..79 -> 0 (written once)
  for (int i=tid; i<16*P; i+=320){
    int r = 64 + i/P, c = i - (i/P)*P;
    vt[r*P + c] = (r==64) ? (u16)0x3F80 : (u16)0;
  }
  f32x4 acc[5][2] = {};
  int s_base = ks*128;
  for (int step=0; step<2; ++step){
    int s0 = s_base + step*64;
    __syncthreads();
    // stage phi^T columns: lane = f within 64-chunk (coalesced 128B reads)
    for (int idx = w; idx < 64*3; idx += 5){
      int s = idx/3, fc = idx - (idx/3)*3;
      int f = fc*64 + lane;
      if (f < FPAD)
        ph[f*P + s] = kphi[(((size_t)(b*TSEQ + s0 + s))*NH + h)*FPAD + f];
    }
    // stage v^T columns: lane = d
    for (int s = w; s < 64; s += 5)
      vt[lane*P + s] = kvb[((size_t)(b*TSEQ + s0 + s))*2048 + 1024 + h*HD + lane];
    __syncthreads();
    #pragma unroll
    for (int k2=0;k2<2;k2++){
      int lk = k2*32 + ((lane>>4)<<3);
      bf16x8 bfr[2];
      #pragma unroll
      for (int n=0;n<2;n++)
        bfr[n] = *(const bf16x8*)(ph + ((w*2+n)*16 + (lane&15))*P + lk);
      #pragma unroll
      for (int m=0;m<5;m++){
        bf16x8 av = *(const bf16x8*)(vt + (m*16 + (lane&15))*P + lk);
        #pragma unroll
        for (int n=0;n<2;n++)
          acc[m][n] = __builtin_amdgcn_mfma_f32_16x16x32_bf16(av, bfr[n], acc[m][n], 0,0,0);
      }
    }
  }
  int rl = (lane>>4)<<2;
  float* pp = part + ((size_t)ks*32 + bh)*80*160;
  #pragma unroll
  for (int m=0;m<5;m++){
    #pragma unroll
    for (int n=0;n<2;n++){
      int f = (w*2+n)*16 + (lane&15);
      #pragma unroll
      for (int r=0;r<4;r++){
        int d = m*16 + rl + r;
        pp[(size_t)d*160 + f] = acc[m][n][r];
      }
    }
  }
}

// ---------------- reduce split-K partials -> kvsT bf16 [bh][80][160] ----------------
__global__ __launch_bounds__(256) void k_kvreduce(const float* __restrict__ part,
    u16* __restrict__ kvsT){
  int i = blockIdx.x*256 + threadIdx.x;  // over 32*80*160 = 409600
  float s = 0.f;
  #pragma unroll
  for (int c=0;c<KSPLIT;c++) s += part[(size_t)c*409600 + i];
  kvsT[i] = f2bf(s);
}

// ---------------- linear attention output: qphi @ [kv_state | k_state], normalize ----------------
__global__ __launch_bounds__(256) void k_linattn(const u16* __restrict__ qphi,
    const u16* __restrict__ kvsT, u16* __restrict__ comb){
  const int LS = 168;
  __shared__ u16 As[64*LS];
  __shared__ u16 Bs[80*LS];
  int bh = blockIdx.x, b = bh>>4, h = bh&15;
  int t0 = blockIdx.y*64;
  int tid = threadIdx.x, lane = tid&63, wid = tid>>6;
  for (int i=tid*8; i<64*FPAD; i+=2048){
    int r = i/FPAD, ff = i - r*FPAD;
    *(bf16x8*)(As + r*LS + ff) = *(const bf16x8*)(qphi + ((size_t)(b*TSEQ + t0 + r)*NH + h)*FPAD + ff);
  }
  for (int i=tid*8; i<80*FPAD; i+=2048){
    int r = i/FPAD, ff = i - r*FPAD;
    *(bf16x8*)(Bs + r*LS + ff) = *(const bf16x8*)(kvsT + (size_t)bh*80*FPAD + i);
  }
  __syncthreads();
  f32x4 acc[5] = {};
  #pragma unroll
  for (int ks=0;ks<5;ks++){
    int lk = ks*32 + ((lane>>4)<<3);
    bf16x8 a = *(const bf16x8*)(As + (wid*16 + (lane&15))*LS + lk);
    #pragma unroll
    for (int n=0;n<5;n++){
      bf16x8 bb = *(const bf16x8*)(Bs + (n*16 + (lane&15))*LS + lk);
      acc[n] = __builtin_amdgcn_mfma_f32_16x16x32_bf16(a, bb, acc[n], 0,0,0);
    }
  }
  int rl = (lane>>4)<<2;
  #pragma unroll
  for (int r=0;r<4;r++){
    float nrm = __shfl(acc[4][r], lane & 48) + 1e-6f;
    float inv = 1.0f / nrm;
    int t = t0 + wid*16 + rl + r;
    #pragma unroll
    for (int n=0;n<4;n++){
      comb[(size_t)(b*TSEQ + t)*2048 + h*64 + n*16 + (lane&15)] = f2bf(acc[n][r]*inv);
    }
  }
}

// ---------------- sliding-window attention (window = 65 incl. self) ----------------
__global__ __launch_bounds__(256) void k_window(const u16* __restrict__ q,
    const u16* __restrict__ kvwin, u16* __restrict__ comb){
  const int LQ = 72, LV = 136;
  __shared__ u16 q_s [64*LQ];
  __shared__ u16 k_s [128*LQ];
  __shared__ u16 vT_s[64*LV];
  __shared__ u16 p_s [64*LV];
  int bh = blockIdx.x, b = bh>>4, h = bh&15;
  int t0 = blockIdx.y*64;
  int tid = threadIdx.x, lane = tid&63, wid = tid>>6;
  int j0 = t0 - 64;
  bf16x8 zv = {0,0,0,0,0,0,0,0};
  for (int cc=tid; cc<512; cc+=256){
    int r = cc>>3, c8 = cc&7;
    *(bf16x8*)(q_s + r*LQ + c8*8) =
      *(const bf16x8*)(q + (size_t)(b*TSEQ + t0 + r)*DM + h*HD + c8*8);
  }
  for (int cc=tid; cc<1024; cc+=256){
    int r = cc>>3, c8 = cc&7;
    int j = j0 + r;
    bf16x8 kv8 = (j>=0) ? *(const bf16x8*)(kvwin + (size_t)(b*TSEQ + j)*2048 + h*HD + c8*8) : zv;
    *(bf16x8*)(k_s + r*LQ + c8*8) = kv8;
    bf16x8 vv8 = (j>=0) ? *(const bf16x8*)(kvwin + (size_t)(b*TSEQ + j)*2048 + 1024 + h*HD + c8*8) : zv;
    #pragma unroll
    for (int e=0;e<8;e++) vT_s[(c8*8+e)*LV + r] = (u16)vv8[e];
  }
  __syncthreads();
  f32x4 sa[8] = {};
  #pragma unroll
  for (int kk=0;kk<64;kk+=32){
    int lk = kk + ((lane>>4)<<3);
    bf16x8 a = *(const bf16x8*)(q_s + (wid*16 + (lane&15))*LQ + lk);
    #pragma unroll
    for (int n=0;n<8;n++){
      bf16x8 bb = *(const bf16x8*)(k_s + (n*16 + (lane&15))*LQ + lk);
      sa[n] = __builtin_amdgcn_mfma_f32_16x16x32_bf16(a, bb, sa[n], 0,0,0);
    }
  }
  int rl = (lane>>4)<<2;
  float pr[8][4];
  #pragma unroll
  for (int r=0;r<4;r++){
    int ig = t0 + wid*16 + rl + r;
    float mx = -1e30f;
    float sv[8];
    #pragma unroll
    for (int n=0;n<8;n++){
      int jg = j0 + n*16 + (lane&15);
      float s = sa[n][r]*0.125f;
      bool ok = (jg>=0) && (jg<=ig) && (jg>=ig-WIN);
      s = ok ? s : -1e30f;
      sv[n]=s; mx = fmaxf(mx, s);
    }
    #pragma unroll
    for (int m=1;m<16;m<<=1) mx = fmaxf(mx, __shfl_xor(mx, m));
    float sum = 0.f;
    #pragma unroll
    for (int n=0;n<8;n++){ float e = __expf(sv[n]-mx); sv[n]=e; sum += e; }
    #pragma unroll
    for (int m=1;m<16;m<<=1) sum += __shfl_xor(sum, m);
    float inv = 1.0f/sum;
    #pragma unroll
    for (int n=0;n<8;n++) pr[n][r] = sv[n]*inv;
  }
  #pragma unroll
  for (int n=0;n<8;n++)
    #pragma unroll
    for (int r=0;r<4;r++)
      p_s[(wid*16 + rl + r)*LV + n*16 + (lane&15)] = f2bf(pr[n][r]);
  __syncthreads();
  f32x4 oa[4] = {};
  #pragma unroll
  for (int ks=0;ks<4;ks++){
    int lk = ks*32 + ((lane>>4)<<3);
    bf16x8 a = *(const bf16x8*)(p_s + (wid*16 + (lane&15))*LV + lk);
    #pragma unroll
    for (int n=0;n<4;n++){
      bf16x8 bb = *(const bf16x8*)(vT_s + (n*16 + (lane&15))*LV + lk);
      oa[n] = __builtin_amdgcn_mfma_f32_16x16x32_bf16(a, bb, oa[n], 0,0,0);
    }
  }
  #pragma unroll
  for (int n=0;n<4;n++)
    #pragma unroll
    for (int r=0;r<4;r++)
      comb[(size_t)(b*TSEQ + t0 + wid*16 + rl + r)*2048 + 1024 + h*HD + n*16 + (lane&15)]
        = f2bf(oa[n][r]);
}

extern "C" void kernel_launch(void* const* d_in, const int* in_sizes, int n_in,
                              void* d_out, int out_size, void* d_ws, size_t ws_size,
                              hipStream_t stream){
  (void)in_sizes; (void)n_in; (void)out_size; (void)ws_size;
  const float* x    = (const float*)d_in[0];
  const float* enc  = (const float*)d_in[1];
  const float* nw   = (const float*)d_in[2];
  const float* Wq   = (const float*)d_in[3];
  const float* Wkv  = (const float*)d_in[4];
  const float* Wqf  = (const float*)d_in[5];
  const float* Wkf  = (const float*)d_in[6];
  const float* Wwin = (const float*)d_in[7];
  const float* Wout = (const float*)d_in[8];
  float* out = (float*)d_out;

  char* p = (char*)d_ws;
  auto alloc = [&](size_t bytes)->char*{
    char* r = p; p += (bytes + 255) & ~(size_t)255; return r;
  };
  // NOTE: part (26.2 MB f32) aliases [xn..WwinT] (27.3 MB) — all five are dead
  // by the time k_kvstate runs (only used by rmsnorm/transposes/first 3 GEMMs).
  char*  aliasBase = p;
  u16*   xn    = (u16*)  alloc((size_t)ROWS*DM*2);
  u16*   encb  = (u16*)  alloc((size_t)ROWS*DM*2);
  u16*   WqT   = (u16*)  alloc((size_t)DM*DM*2);
  u16*   WkvT  = (u16*)  alloc((size_t)2048*DM*2);
  u16*   WwinT = (u16*)  alloc((size_t)2048*DM*2);
  float* part  = (float*)aliasBase;
  u16*   WoutT = (u16*)  alloc((size_t)DM*2048*2);
  u16*   qb    = (u16*)  alloc((size_t)ROWS*DM*2);
  u16*   kvb   = (u16*)  alloc((size_t)ROWS*2048*2);
  u16*   kvwb  = (u16*)  alloc((size_t)ROWS*2048*2);
  u16*   qphi  = (u16*)  alloc((size_t)ROWS*NH*FPAD*2);
  u16*   kphi  = (u16*)  alloc((size_t)ROWS*NH*FPAD*2);
  u16*   kvsT  = (u16*)  alloc((size_t)32*80*FPAD*2);
  u16*   comb  = (u16*)  alloc((size_t)ROWS*2048*2);

  k_rmsnorm<<<ROWS, 256, 0, stream>>>(x, nw, xn);
  k_cast_bf16<<<(ROWS*DM/4 + 255)/256, 256, 0, stream>>>(enc, encb, ROWS*DM/4);
  k_transpose<<<dim3(DM/32,   DM/32),   256, 0, stream>>>(Wq,   WqT,   DM,   DM);
  k_transpose<<<dim3(2048/32, DM/32),   256, 0, stream>>>(Wkv,  WkvT,  DM,   2048);
  k_transpose<<<dim3(2048/32, DM/32),   256, 0, stream>>>(Wwin, WwinT, DM,   2048);
  k_transpose<<<dim3(DM/32,   2048/32), 256, 0, stream>>>(Wout, WoutT, 2048, DM);

  k_gemm<0><<<dim3(ROWS/128, DM/128),   256, 0, stream>>>(xn,   WqT,   qb,   nullptr, nullptr, ROWS, DM,   DM);
  k_gemm<0><<<dim3(ROWS/128, 2048/128), 256, 0, stream>>>(encb, WkvT,  kvb,  nullptr, nullptr, ROWS, 2048, DM);
  k_gemm<0><<<dim3(ROWS/128, 2048/128), 256, 0, stream>>>(xn,   WwinT, kvwb, nullptr, nullptr, ROWS, 2048, DM);

  k_feature<<<ROWS*NH/256, 256, 0, stream>>>(qb,  DM,   Wqf, qphi);
  k_feature<<<ROWS*NH/256, 256, 0, stream>>>(kvb, 2048, Wkf, kphi);

  k_kvstate<<<dim3(32, KSPLIT), 320, 0, stream>>>(kphi, kvb, part);
  k_kvreduce<<<32*80*160/256, 256, 0, stream>>>(part, kvsT);

  k_linattn<<<dim3(32, TSEQ/64), 256, 0, stream>>>(qphi, kvsT, comb);
  k_window <<<dim3(32, TSEQ/64), 256, 0, stream>>>(qb, kvwb, comb);

  k_gemm<1><<<dim3(ROWS/128, DM/128), 256, 0, stream>>>(comb, WoutT, nullptr, out, x, ROWS, DM, 2048);
}

// Round 3
// 267.048 us; speedup vs baseline: 1.4128x; 1.0075x over previous
//
#include <hip/hip_runtime.h>

#define DM 1024
#define NH 16
#define HD 64
#define FD 16
#define NF 153
#define FPAD 160
#define WIN 64
#define TSEQ 2048
#define ROWS 4096
#define KSPLIT 16

typedef unsigned short u16;
typedef __attribute__((ext_vector_type(8))) short bf16x8;
typedef __attribute__((ext_vector_type(8))) unsigned short u16x8;
typedef __attribute__((ext_vector_type(4))) unsigned short u16x4;
typedef __attribute__((ext_vector_type(4))) float f32x4;

#define GLB_AS __attribute__((address_space(1)))
#define LDS_AS __attribute__((address_space(3)))

static __device__ __forceinline__ void gload_lds16(const void* g, void* l){
  __builtin_amdgcn_global_load_lds((const GLB_AS void*)g, (LDS_AS void*)l, 16, 0, 0);
}

static __device__ __forceinline__ float bf2f(u16 u){
  unsigned v = ((unsigned)u) << 16;
  return __builtin_bit_cast(float, v);
}
static __device__ __forceinline__ u16 f2bf(float f){
  unsigned u = __builtin_bit_cast(unsigned, f);
  u += 0x7FFFu + ((u >> 16) & 1u);
  return (u16)(u >> 16);
}

// ---------------- RMSNorm + cast to bf16 ----------------
__global__ __launch_bounds__(256) void k_rmsnorm(const float* __restrict__ x,
    const float* __restrict__ w, u16* __restrict__ out){
  int row = blockIdx.x;
  int tid = threadIdx.x;
  const float4* xr = (const float4*)(x + (size_t)row*DM);
  float4 a = xr[tid];
  float ss = a.x*a.x + a.y*a.y + a.z*a.z + a.w*a.w;
  #pragma unroll
  for (int m=1;m<64;m<<=1) ss += __shfl_xor(ss, m);
  __shared__ float red[4];
  if ((tid&63)==0) red[tid>>6] = ss;
  __syncthreads();
  float tot = red[0]+red[1]+red[2]+red[3];
  float rs = rsqrtf(tot*(1.0f/DM) + 1e-6f);
  float4 wv = ((const float4*)w)[tid];
  u16x4 o;
  o[0] = f2bf(a.x*rs*wv.x);
  o[1] = f2bf(a.y*rs*wv.y);
  o[2] = f2bf(a.z*rs*wv.z);
  o[3] = f2bf(a.w*rs*wv.w);
  ((u16x4*)(out + (size_t)row*DM))[tid] = o;
}

// ---------------- f32 -> bf16 cast ----------------
__global__ __launch_bounds__(256) void k_cast_bf16(const float* __restrict__ in,
    u16* __restrict__ out, int n4){
  int i = blockIdx.x*256 + threadIdx.x;
  if (i >= n4) return;
  float4 a = ((const float4*)in)[i];
  u16x4 o;
  o[0]=f2bf(a.x); o[1]=f2bf(a.y); o[2]=f2bf(a.z); o[3]=f2bf(a.w);
  ((u16x4*)out)[i] = o;
}

// ---------------- transpose + cast: in (K x N) f32 -> out (N x K) bf16 ----------------
__global__ __launch_bounds__(256) void k_transpose(const float* __restrict__ in,
    u16* __restrict__ out, int K, int N){
  __shared__ float t[32][33];
  int n0 = blockIdx.x*32, k0 = blockIdx.y*32;
  int tx = threadIdx.x & 31, ty = threadIdx.x >> 5;
  #pragma unroll
  for (int i=0;i<4;i++) t[ty + i*8][tx] = in[(size_t)(k0 + ty + i*8)*N + n0 + tx];
  __syncthreads();
  #pragma unroll
  for (int i=0;i<4;i++) out[(size_t)(n0 + ty + i*8)*K + k0 + tx] = f2bf(t[tx][ty + i*8]);
}

// ---------------- main GEMM (m97 structure): C(MxN) = A(MxK) * Bt(NxK)^T ----------------
// LDS linear [128][64] bf16 per tile, staged via global_load_lds width=16 with
// inverse-swizzled global source (rule #21); ds_read_b128 applies the same XOR.
template<int EPI>
__global__ __launch_bounds__(256) void k_gemm(const u16* __restrict__ A, const u16* __restrict__ Bt,
    u16* __restrict__ C, float* __restrict__ Cf, const float* __restrict__ resid,
    int M, int N, int K){
  __shared__ u16 As[128*64];
  __shared__ u16 Bs[128*64];
  int row0 = blockIdx.x*128, col0 = blockIdx.y*128;
  int tid = threadIdx.x, lane = tid&63, wid = tid>>6;
  int wr = wid>>1, wc = wid&1;
  // staging geometry: chunk = 1024B = 8 rows of 128B; lane covers (row=lane>>3, 16B slot=lane&7)
  int srow = lane>>3;                     // row within chunk == row&7
  int scb  = ((lane&7)*16) ^ (srow<<4);   // inverse-swizzled byte col (involution)
  f32x4 acc[4][4] = {};
  for (int k0=0;k0<K;k0+=64){
    __syncthreads();
    #pragma unroll
    for (int i=0;i<4;i++){
      int chunk = wid + i*4;              // 16 chunks of 8 rows
      int r = chunk*8 + srow;
      gload_lds16((const char*)(A  + (size_t)(row0+r)*K + k0) + scb,
                  (char*)As + chunk*1024);
      gload_lds16((const char*)(Bt + (size_t)(col0+r)*K + k0) + scb,
                  (char*)Bs + chunk*1024);
    }
    __syncthreads();                      // drains vmcnt -> tiles ready
    #pragma unroll
    for (int kk=0;kk<64;kk+=32){
      int bc = 2*(kk + ((lane>>4)<<3));   // byte col of this lane's 16B fragment
      bf16x8 af[4], bfm[4];
      #pragma unroll
      for (int m=0;m<4;m++){
        int r = wr*64 + m*16 + (lane&15);
        af[m]  = *(const bf16x8*)((const char*)As + r*128 + (bc ^ ((r&7)<<4)));
      }
      #pragma unroll
      for (int n=0;n<4;n++){
        int r = wc*64 + n*16 + (lane&15);
        bfm[n] = *(const bf16x8*)((const char*)Bs + r*128 + (bc ^ ((r&7)<<4)));
      }
      #pragma unroll
      for (int m=0;m<4;m++)
        #pragma unroll
        for (int n=0;n<4;n++)
          acc[m][n] = __builtin_amdgcn_mfma_f32_16x16x32_bf16(af[m], bfm[n], acc[m][n], 0,0,0);
    }
  }
  int rl = (lane>>4)<<2;
  #pragma unroll
  for (int m=0;m<4;m++){
    #pragma unroll
    for (int n=0;n<4;n++){
      int gc = col0 + wc*64 + n*16 + (lane&15);
      #pragma unroll
      for (int r=0;r<4;r++){
        size_t gi = (size_t)(row0 + wr*64 + m*16 + rl + r)*N + gc;
        if constexpr (EPI) Cf[gi] = acc[m][n][r] + resid[gi];
        else               C[gi]  = f2bf(acc[m][n][r]);
      }
    }
  }
}

// ---------------- Taylor feature map (streamed, fully static indexing) ----------------
__global__ __launch_bounds__(256) void k_feature(const u16* __restrict__ X, int ldx,
    const float* __restrict__ W, u16* __restrict__ phi){
  __shared__ float Ws[HD*FD];
  int tid = threadIdx.x;
  for (int i=tid;i<HD*FD;i+=256) Ws[i] = W[i];
  __syncthreads();
  int id = blockIdx.x*256 + tid;
  int h = id & 15;
  size_t row = (size_t)(id >> 4);
  const u16* xp = X + row*ldx + h*HD;
  float f[FD];
  #pragma unroll
  for (int q=0;q<FD;q++) f[q] = 0.f;
  #pragma unroll
  for (int i=0;i<8;i++){
    u16x8 v = *(const u16x8*)(xp + i*8);
    #pragma unroll
    for (int j=0;j<8;j++){
      float xd = bf2f(v[j]);
      const float* wr = &Ws[(i*8+j)*FD];
      #pragma unroll
      for (int q=0;q<FD;q++) f[q] += xd * wr[q];
    }
  }
  u16 buf[FPAD];
  buf[0] = 0x3F80;  // bf16(1.0)
  #pragma unroll
  for (int i=0;i<FD;i++) buf[1+i] = f2bf(f[i]);
  int idx = 1+FD;
  #pragma unroll
  for (int i=0;i<FD;i++){
    #pragma unroll
    for (int j=i;j<FD;j++){
      float sc = (i==j) ? 0.5f : 0.70710678118654752f;
      buf[idx++] = f2bf(f[i]*f[j]*sc);
    }
  }
  #pragma unroll
  for (int z=NF;z<FPAD;z++) buf[z] = 0;
  u16* op = phi + (size_t)id*FPAD;
  #pragma unroll
  for (int c=0;c<FPAD/8;c++){
    u16x8 t;
    #pragma unroll
    for (int j=0;j<8;j++) t[j] = buf[c*8+j];
    *(u16x8*)(op + c*8) = t;
  }
}

// ---------------- kv_state via MFMA, split-K ----------------
__global__ __launch_bounds__(320) void k_kvstate(const u16* __restrict__ kphi,
    const u16* __restrict__ kvb, float* __restrict__ part){
  const int P = 76;
  __shared__ u16 ph[160*P];
  __shared__ u16 vt[80*P];
  int bh = blockIdx.x, b = bh>>4, h = bh&15;
  int ks = blockIdx.y;
  int tid = threadIdx.x, lane = tid&63, w = tid>>6;
  for (int i=tid; i<16*P; i+=320){
    int r = 64 + i/P, c = i - (i/P)*P;
    vt[r*P + c] = (r==64) ? (u16)0x3F80 : (u16)0;
  }
  f32x4 acc[5][2] = {};
  int s_base = ks*128;
  for (int step=0; step<2; ++step){
    int s0 = s_base + step*64;
    __syncthreads();
    for (int idx = w; idx < 64*3; idx += 5){
      int s = idx/3, fc = idx - (idx/3)*3;
      int f = fc*64 + lane;
      if (f < FPAD)
        ph[f*P + s] = kphi[(((size_t)(b*TSEQ + s0 + s))*NH + h)*FPAD + f];
    }
    for (int s = w; s < 64; s += 5)
      vt[lane*P + s] = kvb[((size_t)(b*TSEQ + s0 + s))*2048 + 1024 + h*HD + lane];
    __syncthreads();
    #pragma unroll
    for (int k2=0;k2<2;k2++){
      int lk = k2*32 + ((lane>>4)<<3);
      bf16x8 bfr[2];
      #pragma unroll
      for (int n=0;n<2;n++)
        bfr[n] = *(const bf16x8*)(ph + ((w*2+n)*16 + (lane&15))*P + lk);
      #pragma unroll
      for (int m=0;m<5;m++){
        bf16x8 av = *(const bf16x8*)(vt + (m*16 + (lane&15))*P + lk);
        #pragma unroll
        for (int n=0;n<2;n++)
          acc[m][n] = __builtin_amdgcn_mfma_f32_16x16x32_bf16(av, bfr[n], acc[m][n], 0,0,0);
      }
    }
  }
  int rl = (lane>>4)<<2;
  float* pp = part + ((size_t)ks*32 + bh)*80*160;
  #pragma unroll
  for (int m=0;m<5;m++){
    #pragma unroll
    for (int n=0;n<2;n++){
      int f = (w*2+n)*16 + (lane&15);
      #pragma unroll
      for (int r=0;r<4;r++){
        int d = m*16 + rl + r;
        pp[(size_t)d*160 + f] = acc[m][n][r];
      }
    }
  }
}

// ---------------- reduce split-K partials -> kvsT bf16 [bh][80][160] ----------------
__global__ __launch_bounds__(256) void k_kvreduce(const float* __restrict__ part,
    u16* __restrict__ kvsT){
  int i = blockIdx.x*256 + threadIdx.x;
  float s = 0.f;
  #pragma unroll
  for (int c=0;c<KSPLIT;c++) s += part[(size_t)c*409600 + i];
  kvsT[i] = f2bf(s);
}

// ---------------- linear attention output ----------------
__global__ __launch_bounds__(256) void k_linattn(const u16* __restrict__ qphi,
    const u16* __restrict__ kvsT, u16* __restrict__ comb){
  const int LS = 168;
  __shared__ u16 As[64*LS];
  __shared__ u16 Bs[80*LS];
  int bh = blockIdx.x, b = bh>>4, h = bh&15;
  int t0 = blockIdx.y*64;
  int tid = threadIdx.x, lane = tid&63, wid = tid>>6;
  for (int i=tid*8; i<64*FPAD; i+=2048){
    int r = i/FPAD, ff = i - r*FPAD;
    *(bf16x8*)(As + r*LS + ff) = *(const bf16x8*)(qphi + ((size_t)(b*TSEQ + t0 + r)*NH + h)*FPAD + ff);
  }
  for (int i=tid*8; i<80*FPAD; i+=2048){
    int r = i/FPAD, ff = i - r*FPAD;
    *(bf16x8*)(Bs + r*LS + ff) = *(const bf16x8*)(kvsT + (size_t)bh*80*FPAD + i);
  }
  __syncthreads();
  f32x4 acc[5] = {};
  #pragma unroll
  for (int ks=0;ks<5;ks++){
    int lk = ks*32 + ((lane>>4)<<3);
    bf16x8 a = *(const bf16x8*)(As + (wid*16 + (lane&15))*LS + lk);
    #pragma unroll
    for (int n=0;n<5;n++){
      bf16x8 bb = *(const bf16x8*)(Bs + (n*16 + (lane&15))*LS + lk);
      acc[n] = __builtin_amdgcn_mfma_f32_16x16x32_bf16(a, bb, acc[n], 0,0,0);
    }
  }
  int rl = (lane>>4)<<2;
  #pragma unroll
  for (int r=0;r<4;r++){
    float nrm = __shfl(acc[4][r], lane & 48) + 1e-6f;
    float inv = 1.0f / nrm;
    int t = t0 + wid*16 + rl + r;
    #pragma unroll
    for (int n=0;n<4;n++){
      comb[(size_t)(b*TSEQ + t)*2048 + h*64 + n*16 + (lane&15)] = f2bf(acc[n][r]*inv);
    }
  }
}

// ---------------- sliding-window attention (window = 65 incl. self) ----------------
__global__ __launch_bounds__(256) void k_window(const u16* __restrict__ q,
    const u16* __restrict__ kvwin, u16* __restrict__ comb){
  const int LQ = 72, LV = 136;
  __shared__ u16 q_s [64*LQ];
  __shared__ u16 k_s [128*LQ];
  __shared__ u16 vT_s[64*LV];
  __shared__ u16 p_s [64*LV];
  int bh = blockIdx.x, b = bh>>4, h = bh&15;
  int t0 = blockIdx.y*64;
  int tid = threadIdx.x, lane = tid&63, wid = tid>>6;
  int j0 = t0 - 64;
  bf16x8 zv = {0,0,0,0,0,0,0,0};
  for (int cc=tid; cc<512; cc+=256){
    int r = cc>>3, c8 = cc&7;
    *(bf16x8*)(q_s + r*LQ + c8*8) =
      *(const bf16x8*)(q + (size_t)(b*TSEQ + t0 + r)*DM + h*HD + c8*8);
  }
  for (int cc=tid; cc<1024; cc+=256){
    int r = cc>>3, c8 = cc&7;
    int j = j0 + r;
    bf16x8 kv8 = (j>=0) ? *(const bf16x8*)(kvwin + (size_t)(b*TSEQ + j)*2048 + h*HD + c8*8) : zv;
    *(bf16x8*)(k_s + r*LQ + c8*8) = kv8;
    bf16x8 vv8 = (j>=0) ? *(const bf16x8*)(kvwin + (size_t)(b*TSEQ + j)*2048 + 1024 + h*HD + c8*8) : zv;
    #pragma unroll
    for (int e=0;e<8;e++) vT_s[(c8*8+e)*LV + r] = (u16)vv8[e];
  }
  __syncthreads();
  f32x4 sa[8] = {};
  #pragma unroll
  for (int kk=0;kk<64;kk+=32){
    int lk = kk + ((lane>>4)<<3);
    bf16x8 a = *(const bf16x8*)(q_s + (wid*16 + (lane&15))*LQ + lk);
    #pragma unroll
    for (int n=0;n<8;n++){
      bf16x8 bb = *(const bf16x8*)(k_s + (n*16 + (lane&15))*LQ + lk);
      sa[n] = __builtin_amdgcn_mfma_f32_16x16x32_bf16(a, bb, sa[n], 0,0,0);
    }
  }
  int rl = (lane>>4)<<2;
  float pr[8][4];
  #pragma unroll
  for (int r=0;r<4;r++){
    int ig = t0 + wid*16 + rl + r;
    float mx = -1e30f;
    float sv[8];
    #pragma unroll
    for (int n=0;n<8;n++){
      int jg = j0 + n*16 + (lane&15);
      float s = sa[n][r]*0.125f;
      bool ok = (jg>=0) && (jg<=ig) && (jg>=ig-WIN);
      s = ok ? s : -1e30f;
      sv[n]=s; mx = fmaxf(mx, s);
    }
    #pragma unroll
    for (int m=1;m<16;m<<=1) mx = fmaxf(mx, __shfl_xor(mx, m));
    float sum = 0.f;
    #pragma unroll
    for (int n=0;n<8;n++){ float e = __expf(sv[n]-mx); sv[n]=e; sum += e; }
    #pragma unroll
    for (int m=1;m<16;m<<=1) sum += __shfl_xor(sum, m);
    float inv = 1.0f/sum;
    #pragma unroll
    for (int n=0;n<8;n++) pr[n][r] = sv[n]*inv;
  }
  #pragma unroll
  for (int n=0;n<8;n++)
    #pragma unroll
    for (int r=0;r<4;r++)
      p_s[(wid*16 + rl + r)*LV + n*16 + (lane&15)] = f2bf(pr[n][r]);
  __syncthreads();
  f32x4 oa[4] = {};
  #pragma unroll
  for (int ks=0;ks<4;ks++){
    int lk = ks*32 + ((lane>>4)<<3);
    bf16x8 a = *(const bf16x8*)(p_s + (wid*16 + (lane&15))*LV + lk);
    #pragma unroll
    for (int n=0;n<4;n++){
      bf16x8 bb = *(const bf16x8*)(vT_s + (n*16 + (lane&15))*LV + lk);
      oa[n] = __builtin_amdgcn_mfma_f32_16x16x32_bf16(a, bb, oa[n], 0,0,0);
    }
  }
  #pragma unroll
  for (int n=0;n<4;n++)
    #pragma unroll
    for (int r=0;r<4;r++)
      comb[(size_t)(b*TSEQ + t0 + wid*16 + rl + r)*2048 + 1024 + h*HD + n*16 + (lane&15)]
        = f2bf(oa[n][r]);
}

extern "C" void kernel_launch(void* const* d_in, const int* in_sizes, int n_in,
                              void* d_out, int out_size, void* d_ws, size_t ws_size,
                              hipStream_t stream){
  (void)in_sizes; (void)n_in; (void)out_size; (void)ws_size;
  const float* x    = (const float*)d_in[0];
  const float* enc  = (const float*)d_in[1];
  const float* nw   = (const float*)d_in[2];
  const float* Wq   = (const float*)d_in[3];
  const float* Wkv  = (const float*)d_in[4];
  const float* Wqf  = (const float*)d_in[5];
  const float* Wkf  = (const float*)d_in[6];
  const float* Wwin = (const float*)d_in[7];
  const float* Wout = (const float*)d_in[8];
  float* out = (float*)d_out;

  char* p = (char*)d_ws;
  auto alloc = [&](size_t bytes)->char*{
    char* r = p; p += (bytes + 255) & ~(size_t)255; return r;
  };
  // part (26.2 MB f32) aliases [xn..WwinT] (27.3 MB) — dead by k_kvstate time.
  char*  aliasBase = p;
  u16*   xn    = (u16*)  alloc((size_t)ROWS*DM*2);
  u16*   encb  = (u16*)  alloc((size_t)ROWS*DM*2);
  u16*   WqT   = (u16*)  alloc((size_t)DM*DM*2);
  u16*   WkvT  = (u16*)  alloc((size_t)2048*DM*2);
  u16*   WwinT = (u16*)  alloc((size_t)2048*DM*2);
  float* part  = (float*)aliasBase;
  u16*   WoutT = (u16*)  alloc((size_t)DM*2048*2);
  u16*   qb    = (u16*)  alloc((size_t)ROWS*DM*2);
  u16*   kvb   = (u16*)  alloc((size_t)ROWS*2048*2);
  u16*   kvwb  = (u16*)  alloc((size_t)ROWS*2048*2);
  u16*   qphi  = (u16*)  alloc((size_t)ROWS*NH*FPAD*2);
  u16*   kphi  = (u16*)  alloc((size_t)ROWS*NH*FPAD*2);
  u16*   kvsT  = (u16*)  alloc((size_t)32*80*FPAD*2);
  u16*   comb  = (u16*)  alloc((size_t)ROWS*2048*2);

  k_rmsnorm<<<ROWS, 256, 0, stream>>>(x, nw, xn);
  k_cast_bf16<<<(ROWS*DM/4 + 255)/256, 256, 0, stream>>>(enc, encb, ROWS*DM/4);
  k_transpose<<<dim3(DM/32,   DM/32),   256, 0, stream>>>(Wq,   WqT,   DM,   DM);
  k_transpose<<<dim3(2048/32, DM/32),   256, 0, stream>>>(Wkv,  WkvT,  DM,   2048);
  k_transpose<<<dim3(2048/32, DM/32),   256, 0, stream>>>(Wwin, WwinT, DM,   2048);
  k_transpose<<<dim3(DM/32,   2048/32), 256, 0, stream>>>(Wout, WoutT, 2048, DM);

  k_gemm<0><<<dim3(ROWS/128, DM/128),   256, 0, stream>>>(xn,   WqT,   qb,   nullptr, nullptr, ROWS, DM,   DM);
  k_gemm<0><<<dim3(ROWS/128, 2048/128), 256, 0, stream>>>(encb, WkvT,  kvb,  nullptr, nullptr, ROWS, 2048, DM);
  k_gemm<0><<<dim3(ROWS/128, 2048/128), 256, 0, stream>>>(xn,   WwinT, kvwb, nullptr, nullptr, ROWS, 2048, DM);

  k_feature<<<ROWS*NH/256, 256, 0, stream>>>(qb,  DM,   Wqf, qphi);
  k_feature<<<ROWS*NH/256, 256, 0, stream>>>(kvb, 2048, Wkf, kphi);

  k_kvstate<<<dim3(32, KSPLIT), 320, 0, stream>>>(kphi, kvb, part);
  k_kvreduce<<<32*80*160/256, 256, 0, stream>>>(part, kvsT);

  k_linattn<<<dim3(32, TSEQ/64), 256, 0, stream>>>(qphi, kvsT, comb);
  k_window <<<dim3(32, TSEQ/64), 256, 0, stream>>>(qb, kvwb, comb);

  k_gemm<1><<<dim3(ROWS/128, DM/128), 256, 0, stream>>>(comb, WoutT, nullptr, out, x, ROWS, DM, 2048);
}

// Round 4
// 231.592 us; speedup vs baseline: 1.6291x; 1.1531x over previous
//
#include <hip/hip_runtime.h>

#define DM 1024
#define NH 16
#define HD 64
#define FD 16
#define NF 153
#define FPAD 160
#define WIN 64
#define TSEQ 2048
#define ROWS 4096
#define KSPLIT 16

typedef unsigned short u16;
typedef __attribute__((ext_vector_type(8))) short bf16x8;
typedef __attribute__((ext_vector_type(8))) unsigned short u16x8;
typedef __attribute__((ext_vector_type(4))) unsigned short u16x4;
typedef __attribute__((ext_vector_type(4))) float f32x4;

#define GLB_AS __attribute__((address_space(1)))
#define LDS_AS __attribute__((address_space(3)))

static __device__ __forceinline__ void gload_lds16(const void* g, void* l){
  __builtin_amdgcn_global_load_lds((const GLB_AS void*)g, (LDS_AS void*)l, 16, 0, 0);
}

static __device__ __forceinline__ float bf2f(u16 u){
  unsigned v = ((unsigned)u) << 16;
  return __builtin_bit_cast(float, v);
}
static __device__ __forceinline__ u16 f2bf(float f){
  unsigned u = __builtin_bit_cast(unsigned, f);
  u += 0x7FFFu + ((u >> 16) & 1u);
  return (u16)(u >> 16);
}

// ---------------- RMSNorm + cast to bf16 ----------------
__global__ __launch_bounds__(256) void k_rmsnorm(const float* __restrict__ x,
    const float* __restrict__ w, u16* __restrict__ out){
  int row = blockIdx.x;
  int tid = threadIdx.x;
  const float4* xr = (const float4*)(x + (size_t)row*DM);
  float4 a = xr[tid];
  float ss = a.x*a.x + a.y*a.y + a.z*a.z + a.w*a.w;
  #pragma unroll
  for (int m=1;m<64;m<<=1) ss += __shfl_xor(ss, m);
  __shared__ float red[4];
  if ((tid&63)==0) red[tid>>6] = ss;
  __syncthreads();
  float tot = red[0]+red[1]+red[2]+red[3];
  float rs = rsqrtf(tot*(1.0f/DM) + 1e-6f);
  float4 wv = ((const float4*)w)[tid];
  u16x4 o;
  o[0] = f2bf(a.x*rs*wv.x);
  o[1] = f2bf(a.y*rs*wv.y);
  o[2] = f2bf(a.z*rs*wv.z);
  o[3] = f2bf(a.w*rs*wv.w);
  ((u16x4*)(out + (size_t)row*DM))[tid] = o;
}

// ---------------- f32 -> bf16 cast ----------------
__global__ __launch_bounds__(256) void k_cast_bf16(const float* __restrict__ in,
    u16* __restrict__ out, int n4){
  int i = blockIdx.x*256 + threadIdx.x;
  if (i >= n4) return;
  float4 a = ((const float4*)in)[i];
  u16x4 o;
  o[0]=f2bf(a.x); o[1]=f2bf(a.y); o[2]=f2bf(a.z); o[3]=f2bf(a.w);
  ((u16x4*)out)[i] = o;
}

// ---------------- transpose + cast: in (K x N) f32 -> out (N x K) bf16 ----------------
__global__ __launch_bounds__(256) void k_transpose(const float* __restrict__ in,
    u16* __restrict__ out, int K, int N){
  __shared__ float t[32][33];
  int n0 = blockIdx.x*32, k0 = blockIdx.y*32;
  int tx = threadIdx.x & 31, ty = threadIdx.x >> 5;
  #pragma unroll
  for (int i=0;i<4;i++) t[ty + i*8][tx] = in[(size_t)(k0 + ty + i*8)*N + n0 + tx];
  __syncthreads();
  #pragma unroll
  for (int i=0;i<4;i++) out[(size_t)(n0 + ty + i*8)*K + k0 + tx] = f2bf(t[tx][ty + i*8]);
}

// ---------------- batched pipelined GEMM ----------------
// C = A(128-row panel) * Bt(128-col panel)^T, K common. Two param sets picked by
// blockIdx.y < split. Double-buffered LDS, counted vmcnt(8) so next tile's
// global_load_lds stay in flight across the barrier (never vmcnt(0) in loop).
template<int EPI>
__global__ __launch_bounds__(256) void k_gemm(
    const u16* __restrict__ A0, const u16* __restrict__ B0, u16* __restrict__ C0, int ldc0,
    const u16* __restrict__ A1, const u16* __restrict__ B1, u16* __restrict__ C1, int ldc1,
    int split, int K, float* __restrict__ Cf, const float* __restrict__ resid){
  __shared__ u16 As0[128*64];
  __shared__ u16 Bs0[128*64];
  __shared__ u16 As1[128*64];
  __shared__ u16 Bs1[128*64];
  int by = blockIdx.y;
  const u16 *A, *Bt; u16* C; int ldc;
  if (by < split){ A=A0; Bt=B0; C=C0; ldc=ldc0; }
  else { by -= split; A=A1; Bt=B1; C=C1; ldc=ldc1; }
  int row0 = blockIdx.x*128, col0 = by*128;
  int tid = threadIdx.x, lane = tid&63, wid = tid>>6;
  int wr = wid>>1, wc = wid&1;
  // staging geometry: chunk = 1024B = 8 rows of 128B; lane covers (row=lane>>3, slot=lane&7)
  int srow = lane>>3;
  int scb  = ((lane&7)*16) ^ (srow<<4);   // inverse-swizzled source byte col
  f32x4 acc[4][4] = {};

  auto STAGE = [&](u16* Asb, u16* Bsb, int k0){
    #pragma unroll
    for (int i=0;i<4;i++){
      int chunk = wid + i*4;
      int r = chunk*8 + srow;
      gload_lds16((const char*)(A  + (size_t)(row0+r)*K + k0) + scb, (char*)Asb + chunk*1024);
      gload_lds16((const char*)(Bt + (size_t)(col0+r)*K + k0) + scb, (char*)Bsb + chunk*1024);
    }
  };
  auto COMPUTE = [&](const u16* Asb, const u16* Bsb){
    #pragma unroll
    for (int kk=0;kk<64;kk+=32){
      int bc = 2*(kk + ((lane>>4)<<3));
      bf16x8 af[4], bfm[4];
      #pragma unroll
      for (int m=0;m<4;m++){
        int r = wr*64 + m*16 + (lane&15);
        af[m]  = *(const bf16x8*)((const char*)Asb + r*128 + (bc ^ ((r&7)<<4)));
      }
      #pragma unroll
      for (int n=0;n<4;n++){
        int r = wc*64 + n*16 + (lane&15);
        bfm[n] = *(const bf16x8*)((const char*)Bsb + r*128 + (bc ^ ((r&7)<<4)));
      }
      #pragma unroll
      for (int m=0;m<4;m++)
        #pragma unroll
        for (int n=0;n<4;n++)
          acc[m][n] = __builtin_amdgcn_mfma_f32_16x16x32_bf16(af[m], bfm[n], acc[m][n], 0,0,0);
    }
  };

  int nt = K >> 6;          // always even here (16 or 32)
  STAGE(As0, Bs0, 0);
  for (int t=0; t<nt-2; t+=2){
    STAGE(As1, Bs1, (t+1)*64);
    asm volatile("s_waitcnt vmcnt(8)" ::: "memory");
    __builtin_amdgcn_s_barrier();
    COMPUTE(As0, Bs0);
    __builtin_amdgcn_s_barrier();
    STAGE(As0, Bs0, (t+2)*64);
    asm volatile("s_waitcnt vmcnt(8)" ::: "memory");
    __builtin_amdgcn_s_barrier();
    COMPUTE(As1, Bs1);
    __builtin_amdgcn_s_barrier();
  }
  STAGE(As1, Bs1, (nt-1)*64);
  asm volatile("s_waitcnt vmcnt(8)" ::: "memory");
  __builtin_amdgcn_s_barrier();
  COMPUTE(As0, Bs0);
  asm volatile("s_waitcnt vmcnt(0)" ::: "memory");
  __builtin_amdgcn_s_barrier();
  COMPUTE(As1, Bs1);

  int rl = (lane>>4)<<2;
  #pragma unroll
  for (int m=0;m<4;m++){
    #pragma unroll
    for (int n=0;n<4;n++){
      int gc = col0 + wc*64 + n*16 + (lane&15);
      #pragma unroll
      for (int r=0;r<4;r++){
        size_t gi = (size_t)(row0 + wr*64 + m*16 + rl + r)*ldc + gc;
        if constexpr (EPI) Cf[gi] = acc[m][n][r] + resid[gi];
        else               C[gi]  = f2bf(acc[m][n][r]);
      }
    }
  }
}

// ---------------- Taylor feature map (streamed, fully static indexing) ----------------
__global__ __launch_bounds__(256) void k_feature(const u16* __restrict__ X, int ldx,
    const float* __restrict__ W, u16* __restrict__ phi){
  __shared__ float Ws[HD*FD];
  int tid = threadIdx.x;
  for (int i=tid;i<HD*FD;i+=256) Ws[i] = W[i];
  __syncthreads();
  int id = blockIdx.x*256 + tid;
  int h = id & 15;
  size_t row = (size_t)(id >> 4);
  const u16* xp = X + row*ldx + h*HD;
  float f[FD];
  #pragma unroll
  for (int q=0;q<FD;q++) f[q] = 0.f;
  #pragma unroll
  for (int i=0;i<8;i++){
    u16x8 v = *(const u16x8*)(xp + i*8);
    #pragma unroll
    for (int j=0;j<8;j++){
      float xd = bf2f(v[j]);
      const float* wr = &Ws[(i*8+j)*FD];
      #pragma unroll
      for (int q=0;q<FD;q++) f[q] += xd * wr[q];
    }
  }
  u16 buf[FPAD];
  buf[0] = 0x3F80;  // bf16(1.0)
  #pragma unroll
  for (int i=0;i<FD;i++) buf[1+i] = f2bf(f[i]);
  int idx = 1+FD;
  #pragma unroll
  for (int i=0;i<FD;i++){
    #pragma unroll
    for (int j=i;j<FD;j++){
      float sc = (i==j) ? 0.5f : 0.70710678118654752f;
      buf[idx++] = f2bf(f[i]*f[j]*sc);
    }
  }
  #pragma unroll
  for (int z=NF;z<FPAD;z++) buf[z] = 0;
  u16* op = phi + (size_t)id*FPAD;
  #pragma unroll
  for (int c=0;c<FPAD/8;c++){
    u16x8 t;
    #pragma unroll
    for (int j=0;j<8;j++) t[j] = buf[c*8+j];
    *(u16x8*)(op + c*8) = t;
  }
}

// ---------------- kv_state via MFMA, split-K ----------------
__global__ __launch_bounds__(320) void k_kvstate(const u16* __restrict__ kphi,
    const u16* __restrict__ kvb, float* __restrict__ part){
  const int P = 76;
  __shared__ u16 ph[160*P];
  __shared__ u16 vt[80*P];
  int bh = blockIdx.x, b = bh>>4, h = bh&15;
  int ks = blockIdx.y;
  int tid = threadIdx.x, lane = tid&63, w = tid>>6;
  for (int i=tid; i<16*P; i+=320){
    int r = 64 + i/P, c = i - (i/P)*P;
    vt[r*P + c] = (r==64) ? (u16)0x3F80 : (u16)0;
  }
  f32x4 acc[5][2] = {};
  int s_base = ks*128;
  for (int step=0; step<2; ++step){
    int s0 = s_base + step*64;
    __syncthreads();
    for (int idx = w; idx < 64*3; idx += 5){
      int s = idx/3, fc = idx - (idx/3)*3;
      int f = fc*64 + lane;
      if (f < FPAD)
        ph[f*P + s] = kphi[(((size_t)(b*TSEQ + s0 + s))*NH + h)*FPAD + f];
    }
    for (int s = w; s < 64; s += 5)
      vt[lane*P + s] = kvb[((size_t)(b*TSEQ + s0 + s))*2048 + 1024 + h*HD + lane];
    __syncthreads();
    #pragma unroll
    for (int k2=0;k2<2;k2++){
      int lk = k2*32 + ((lane>>4)<<3);
      bf16x8 bfr[2];
      #pragma unroll
      for (int n=0;n<2;n++)
        bfr[n] = *(const bf16x8*)(ph + ((w*2+n)*16 + (lane&15))*P + lk);
      #pragma unroll
      for (int m=0;m<5;m++){
        bf16x8 av = *(const bf16x8*)(vt + (m*16 + (lane&15))*P + lk);
        #pragma unroll
        for (int n=0;n<2;n++)
          acc[m][n] = __builtin_amdgcn_mfma_f32_16x16x32_bf16(av, bfr[n], acc[m][n], 0,0,0);
      }
    }
  }
  int rl = (lane>>4)<<2;
  float* pp = part + ((size_t)ks*32 + bh)*80*160;
  #pragma unroll
  for (int m=0;m<5;m++){
    #pragma unroll
    for (int n=0;n<2;n++){
      int f = (w*2+n)*16 + (lane&15);
      #pragma unroll
      for (int r=0;r<4;r++){
        int d = m*16 + rl + r;
        pp[(size_t)d*160 + f] = acc[m][n][r];
      }
    }
  }
}

// ---------------- reduce split-K partials -> kvsT bf16 [bh][80][160] ----------------
__global__ __launch_bounds__(256) void k_kvreduce(const float* __restrict__ part,
    u16* __restrict__ kvsT){
  int i = blockIdx.x*256 + threadIdx.x;
  float s = 0.f;
  #pragma unroll
  for (int c=0;c<KSPLIT;c++) s += part[(size_t)c*409600 + i];
  kvsT[i] = f2bf(s);
}

// ---------------- linear attention output ----------------
__global__ __launch_bounds__(256) void k_linattn(const u16* __restrict__ qphi,
    const u16* __restrict__ kvsT, u16* __restrict__ comb){
  const int LS = 168;
  __shared__ u16 As[64*LS];
  __shared__ u16 Bs[80*LS];
  int bh = blockIdx.x, b = bh>>4, h = bh&15;
  int t0 = blockIdx.y*64;
  int tid = threadIdx.x, lane = tid&63, wid = tid>>6;
  for (int i=tid*8; i<64*FPAD; i+=2048){
    int r = i/FPAD, ff = i - r*FPAD;
    *(bf16x8*)(As + r*LS + ff) = *(const bf16x8*)(qphi + ((size_t)(b*TSEQ + t0 + r)*NH + h)*FPAD + ff);
  }
  for (int i=tid*8; i<80*FPAD; i+=2048){
    int r = i/FPAD, ff = i - r*FPAD;
    *(bf16x8*)(Bs + r*LS + ff) = *(const bf16x8*)(kvsT + (size_t)bh*80*FPAD + i);
  }
  __syncthreads();
  f32x4 acc[5] = {};
  #pragma unroll
  for (int ks=0;ks<5;ks++){
    int lk = ks*32 + ((lane>>4)<<3);
    bf16x8 a = *(const bf16x8*)(As + (wid*16 + (lane&15))*LS + lk);
    #pragma unroll
    for (int n=0;n<5;n++){
      bf16x8 bb = *(const bf16x8*)(Bs + (n*16 + (lane&15))*LS + lk);
      acc[n] = __builtin_amdgcn_mfma_f32_16x16x32_bf16(a, bb, acc[n], 0,0,0);
    }
  }
  int rl = (lane>>4)<<2;
  #pragma unroll
  for (int r=0;r<4;r++){
    float nrm = __shfl(acc[4][r], lane & 48) + 1e-6f;
    float inv = 1.0f / nrm;
    int t = t0 + wid*16 + rl + r;
    #pragma unroll
    for (int n=0;n<4;n++){
      comb[(size_t)(b*TSEQ + t)*2048 + h*64 + n*16 + (lane&15)] = f2bf(acc[n][r]*inv);
    }
  }
}

// ---------------- sliding-window attention (window = 65 incl. self) ----------------
__global__ __launch_bounds__(256) void k_window(const u16* __restrict__ q, int ldq,
    const u16* __restrict__ kvwin, int ldkv, u16* __restrict__ comb){
  const int LQ = 72, LV = 136;
  __shared__ u16 q_s [64*LQ];
  __shared__ u16 k_s [128*LQ];
  __shared__ u16 vT_s[64*LV];
  __shared__ u16 p_s [64*LV];
  int bh = blockIdx.x, b = bh>>4, h = bh&15;
  int t0 = blockIdx.y*64;
  int tid = threadIdx.x, lane = tid&63, wid = tid>>6;
  int j0 = t0 - 64;
  bf16x8 zv = {0,0,0,0,0,0,0,0};
  for (int cc=tid; cc<512; cc+=256){
    int r = cc>>3, c8 = cc&7;
    *(bf16x8*)(q_s + r*LQ + c8*8) =
      *(const bf16x8*)(q + (size_t)(b*TSEQ + t0 + r)*ldq + h*HD + c8*8);
  }
  for (int cc=tid; cc<1024; cc+=256){
    int r = cc>>3, c8 = cc&7;
    int j = j0 + r;
    bf16x8 kv8 = (j>=0) ? *(const bf16x8*)(kvwin + (size_t)(b*TSEQ + j)*ldkv + h*HD + c8*8) : zv;
    *(bf16x8*)(k_s + r*LQ + c8*8) = kv8;
    bf16x8 vv8 = (j>=0) ? *(const bf16x8*)(kvwin + (size_t)(b*TSEQ + j)*ldkv + 1024 + h*HD + c8*8) : zv;
    #pragma unroll
    for (int e=0;e<8;e++) vT_s[(c8*8+e)*LV + r] = (u16)vv8[e];
  }
  __syncthreads();
  f32x4 sa[8] = {};
  #pragma unroll
  for (int kk=0;kk<64;kk+=32){
    int lk = kk + ((lane>>4)<<3);
    bf16x8 a = *(const bf16x8*)(q_s + (wid*16 + (lane&15))*LQ + lk);
    #pragma unroll
    for (int n=0;n<8;n++){
      bf16x8 bb = *(const bf16x8*)(k_s + (n*16 + (lane&15))*LQ + lk);
      sa[n] = __builtin_amdgcn_mfma_f32_16x16x32_bf16(a, bb, sa[n], 0,0,0);
    }
  }
  int rl = (lane>>4)<<2;
  float pr[8][4];
  #pragma unroll
  for (int r=0;r<4;r++){
    int ig = t0 + wid*16 + rl + r;
    float mx = -1e30f;
    float sv[8];
    #pragma unroll
    for (int n=0;n<8;n++){
      int jg = j0 + n*16 + (lane&15);
      float s = sa[n][r]*0.125f;
      bool ok = (jg>=0) && (jg<=ig) && (jg>=ig-WIN);
      s = ok ? s : -1e30f;
      sv[n]=s; mx = fmaxf(mx, s);
    }
    #pragma unroll
    for (int m=1;m<16;m<<=1) mx = fmaxf(mx, __shfl_xor(mx, m));
    float sum = 0.f;
    #pragma unroll
    for (int n=0;n<8;n++){ float e = __expf(sv[n]-mx); sv[n]=e; sum += e; }
    #pragma unroll
    for (int m=1;m<16;m<<=1) sum += __shfl_xor(sum, m);
    float inv = 1.0f/sum;
    #pragma unroll
    for (int n=0;n<8;n++) pr[n][r] = sv[n]*inv;
  }
  #pragma unroll
  for (int n=0;n<8;n++)
    #pragma unroll
    for (int r=0;r<4;r++)
      p_s[(wid*16 + rl + r)*LV + n*16 + (lane&15)] = f2bf(pr[n][r]);
  __syncthreads();
  f32x4 oa[4] = {};
  #pragma unroll
  for (int ks=0;ks<4;ks++){
    int lk = ks*32 + ((lane>>4)<<3);
    bf16x8 a = *(const bf16x8*)(p_s + (wid*16 + (lane&15))*LV + lk);
    #pragma unroll
    for (int n=0;n<4;n++){
      bf16x8 bb = *(const bf16x8*)(vT_s + (n*16 + (lane&15))*LV + lk);
      oa[n] = __builtin_amdgcn_mfma_f32_16x16x32_bf16(a, bb, oa[n], 0,0,0);
    }
  }
  #pragma unroll
  for (int n=0;n<4;n++)
    #pragma unroll
    for (int r=0;r<4;r++)
      comb[(size_t)(b*TSEQ + t0 + wid*16 + rl + r)*2048 + 1024 + h*HD + n*16 + (lane&15)]
        = f2bf(oa[n][r]);
}

extern "C" void kernel_launch(void* const* d_in, const int* in_sizes, int n_in,
                              void* d_out, int out_size, void* d_ws, size_t ws_size,
                              hipStream_t stream){
  (void)in_sizes; (void)n_in; (void)out_size; (void)ws_size;
  const float* x    = (const float*)d_in[0];
  const float* enc  = (const float*)d_in[1];
  const float* nw   = (const float*)d_in[2];
  const float* Wq   = (const float*)d_in[3];
  const float* Wkv  = (const float*)d_in[4];
  const float* Wqf  = (const float*)d_in[5];
  const float* Wkf  = (const float*)d_in[6];
  const float* Wwin = (const float*)d_in[7];
  const float* Wout = (const float*)d_in[8];
  float* out = (float*)d_out;

  char* p = (char*)d_ws;
  auto alloc = [&](size_t bytes)->char*{
    char* r = p; p += (bytes + 255) & ~(size_t)255; return r;
  };
  // part (26.2 MB f32) aliases [xn..WkvT] (27.3 MB) — all dead before k_kvstate.
  char*  aliasBase = p;
  u16*   xn    = (u16*)  alloc((size_t)ROWS*DM*2);
  u16*   encb  = (u16*)  alloc((size_t)ROWS*DM*2);
  u16*   WqwT  = (u16*)  alloc((size_t)3072*DM*2);   // rows 0..1023 Wq^T, 1024..3071 Wwin^T
  u16*   WkvT  = (u16*)  alloc((size_t)2048*DM*2);
  float* part  = (float*)aliasBase;
  u16*   WoutT = (u16*)  alloc((size_t)DM*2048*2);
  u16*   qwin  = (u16*)  alloc((size_t)ROWS*3072*2); // [q | k_win | v_win], ld 3072
  u16*   kvb   = (u16*)  alloc((size_t)ROWS*2048*2);
  u16*   qphi  = (u16*)  alloc((size_t)ROWS*NH*FPAD*2);
  u16*   kphi  = (u16*)  alloc((size_t)ROWS*NH*FPAD*2);
  u16*   kvsT  = (u16*)  alloc((size_t)32*80*FPAD*2);
  u16*   comb  = (u16*)  alloc((size_t)ROWS*2048*2);

  k_rmsnorm<<<ROWS, 256, 0, stream>>>(x, nw, xn);
  k_cast_bf16<<<(ROWS*DM/4 + 255)/256, 256, 0, stream>>>(enc, encb, ROWS*DM/4);
  k_transpose<<<dim3(32, 32), 256, 0, stream>>>(Wq,   WqwT,                        DM,   DM);
  k_transpose<<<dim3(64, 32), 256, 0, stream>>>(Wwin, WqwT + (size_t)1024*DM,      DM,   2048);
  k_transpose<<<dim3(64, 32), 256, 0, stream>>>(Wkv,  WkvT,                        DM,   2048);
  k_transpose<<<dim3(32, 64), 256, 0, stream>>>(Wout, WoutT,                       2048, DM);

  // batched projections: by<24 -> xn@WqwT -> qwin (ld 3072); else encb@WkvT -> kvb (ld 2048)
  k_gemm<0><<<dim3(ROWS/128, 40), 256, 0, stream>>>(
      xn, WqwT, qwin, 3072,  encb, WkvT, kvb, 2048,  24, DM, nullptr, nullptr);

  k_feature<<<ROWS*NH/256, 256, 0, stream>>>(qwin, 3072, Wqf, qphi);
  k_feature<<<ROWS*NH/256, 256, 0, stream>>>(kvb,  2048, Wkf, kphi);

  k_kvstate<<<dim3(32, KSPLIT), 320, 0, stream>>>(kphi, kvb, part);
  k_kvreduce<<<32*80*160/256, 256, 0, stream>>>(part, kvsT);

  k_linattn<<<dim3(32, TSEQ/64), 256, 0, stream>>>(qphi, kvsT, comb);
  k_window <<<dim3(32, TSEQ/64), 256, 0, stream>>>(qwin, 3072, qwin + 1024, 3072, comb);

  // Wout GEMM with fused residual epilogue
  k_gemm<1><<<dim3(ROWS/128, 8), 256, 0, stream>>>(
      comb, WoutT, nullptr, DM,  nullptr, nullptr, nullptr, 0,  8, 2048, out, x);
}

// Round 5
// 171.182 us; speedup vs baseline: 2.2040x; 1.3529x over previous
//
#include <hip/hip_runtime.h>

#define DM 1024
#define NH 16
#define HD 64
#define FD 16
#define NF 153
#define FPAD 160
#define WIN 64
#define TSEQ 2048
#define ROWS 4096
#define KSPLIT 8
#define RS2 0.70710678118654752f

typedef unsigned short u16;
typedef __attribute__((ext_vector_type(8))) short bf16x8;
typedef __attribute__((ext_vector_type(8))) unsigned short u16x8;
typedef __attribute__((ext_vector_type(4))) unsigned short u16x4;
typedef __attribute__((ext_vector_type(4))) float f32x4;

#define GLB_AS __attribute__((address_space(1)))
#define LDS_AS __attribute__((address_space(3)))

static __device__ __forceinline__ void gload_lds16(const void* g, void* l){
  __builtin_amdgcn_global_load_lds((const GLB_AS void*)g, (LDS_AS void*)l, 16, 0, 0);
}

static __device__ __forceinline__ float bf2f(u16 u){
  unsigned v = ((unsigned)u) << 16;
  return __builtin_bit_cast(float, v);
}
static __device__ __forceinline__ u16 f2bf(float f){
  unsigned u = __builtin_bit_cast(unsigned, f);
  u += 0x7FFFu + ((u >> 16) & 1u);
  return (u16)(u >> 16);
}

// ---------------- RMSNorm (by=0) + enc cast (by=1) ----------------
__global__ __launch_bounds__(256) void k_prep(const float* __restrict__ x,
    const float* __restrict__ enc, const float* __restrict__ w,
    u16* __restrict__ xn, u16* __restrict__ encb){
  int row = blockIdx.x, tid = threadIdx.x;
  if (blockIdx.y == 0){
    const float4* xr = (const float4*)(x + (size_t)row*DM);
    float4 a = xr[tid];
    float ss = a.x*a.x + a.y*a.y + a.z*a.z + a.w*a.w;
    #pragma unroll
    for (int m=1;m<64;m<<=1) ss += __shfl_xor(ss, m);
    __shared__ float red[4];
    if ((tid&63)==0) red[tid>>6] = ss;
    __syncthreads();
    float tot = red[0]+red[1]+red[2]+red[3];
    float rs = rsqrtf(tot*(1.0f/DM) + 1e-6f);
    float4 wv = ((const float4*)w)[tid];
    u16x4 o;
    o[0]=f2bf(a.x*rs*wv.x); o[1]=f2bf(a.y*rs*wv.y);
    o[2]=f2bf(a.z*rs*wv.z); o[3]=f2bf(a.w*rs*wv.w);
    ((u16x4*)(xn + (size_t)row*DM))[tid] = o;
  } else {
    float4 a = ((const float4*)(enc + (size_t)row*DM))[tid];
    u16x4 o;
    o[0]=f2bf(a.x); o[1]=f2bf(a.y); o[2]=f2bf(a.z); o[3]=f2bf(a.w);
    ((u16x4*)(encb + (size_t)row*DM))[tid] = o;
  }
}

// ---------------- all weight packing in one dispatch ----------------
static __device__ __forceinline__ void tr_tile(const float* __restrict__ in,
    u16* __restrict__ out, int K, int N, int n0, int k0, float* t, int tid){
  int tx = tid & 31, ty = tid >> 5;
  #pragma unroll
  for (int i=0;i<4;i++) t[(ty + i*8)*33 + tx] = in[(size_t)(k0 + ty + i*8)*N + n0 + tx];
  __syncthreads();
  #pragma unroll
  for (int i=0;i<4;i++) out[(size_t)(n0 + ty + i*8)*K + k0 + tx] = f2bf(t[tx*33 + ty + i*8]);
}

__global__ __launch_bounds__(256) void k_packw(const float* __restrict__ Wq,
    const float* __restrict__ Wwin, const float* __restrict__ Wkv,
    const float* __restrict__ Wout, const float* __restrict__ Wqf,
    const float* __restrict__ Wkf, u16* __restrict__ WqwT, u16* __restrict__ WkvT,
    u16* __restrict__ WoutT, u16* __restrict__ WqfT, u16* __restrict__ WkfT){
  __shared__ float t[32*33];
  int b = blockIdx.x, tid = threadIdx.x;
  if (b < 1024){
    tr_tile(Wq, WqwT, 1024, 1024, (b&31)*32, (b>>5)*32, t, tid);
  } else if (b < 3072){
    int r = b-1024;
    tr_tile(Wwin, WqwT + (size_t)1024*1024, 1024, 2048, (r&63)*32, (r>>6)*32, t, tid);
  } else if (b < 5120){
    int r = b-3072;
    tr_tile(Wkv, WkvT, 1024, 2048, (r&63)*32, (r>>6)*32, t, tid);
  } else if (b < 7168){
    int r = b-5120;
    tr_tile(Wout, WoutT, 2048, 1024, (r&31)*32, (r>>5)*32, t, tid);
  } else {
    const float* src = (b==7168) ? Wqf : Wkf;
    u16* dst = (b==7168) ? WqfT : WkfT;
    for (int i=tid;i<1024;i+=256) dst[i] = f2bf(src[(i&63)*16 + (i>>6)]);
  }
}

// ---------------- batched pipelined GEMM (unchanged from R4) ----------------
template<int EPI>
__global__ __launch_bounds__(256) void k_gemm(
    const u16* __restrict__ A0, const u16* __restrict__ B0, u16* __restrict__ C0, int ldc0,
    const u16* __restrict__ A1, const u16* __restrict__ B1, u16* __restrict__ C1, int ldc1,
    int split, int K, float* __restrict__ Cf, const float* __restrict__ resid){
  __shared__ u16 As0[128*64];
  __shared__ u16 Bs0[128*64];
  __shared__ u16 As1[128*64];
  __shared__ u16 Bs1[128*64];
  int by = blockIdx.y;
  const u16 *A, *Bt; u16* C; int ldc;
  if (by < split){ A=A0; Bt=B0; C=C0; ldc=ldc0; }
  else { by -= split; A=A1; Bt=B1; C=C1; ldc=ldc1; }
  int row0 = blockIdx.x*128, col0 = by*128;
  int tid = threadIdx.x, lane = tid&63, wid = tid>>6;
  int wr = wid>>1, wc = wid&1;
  int srow = lane>>3;
  int scb  = ((lane&7)*16) ^ (srow<<4);
  f32x4 acc[4][4] = {};

  auto STAGE = [&](u16* Asb, u16* Bsb, int k0){
    #pragma unroll
    for (int i=0;i<4;i++){
      int chunk = wid + i*4;
      int r = chunk*8 + srow;
      gload_lds16((const char*)(A  + (size_t)(row0+r)*K + k0) + scb, (char*)Asb + chunk*1024);
      gload_lds16((const char*)(Bt + (size_t)(col0+r)*K + k0) + scb, (char*)Bsb + chunk*1024);
    }
  };
  auto COMPUTE = [&](const u16* Asb, const u16* Bsb){
    #pragma unroll
    for (int kk=0;kk<64;kk+=32){
      int bc = 2*(kk + ((lane>>4)<<3));
      bf16x8 af[4], bfm[4];
      #pragma unroll
      for (int m=0;m<4;m++){
        int r = wr*64 + m*16 + (lane&15);
        af[m]  = *(const bf16x8*)((const char*)Asb + r*128 + (bc ^ ((r&7)<<4)));
      }
      #pragma unroll
      for (int n=0;n<4;n++){
        int r = wc*64 + n*16 + (lane&15);
        bfm[n] = *(const bf16x8*)((const char*)Bsb + r*128 + (bc ^ ((r&7)<<4)));
      }
      #pragma unroll
      for (int m=0;m<4;m++)
        #pragma unroll
        for (int n=0;n<4;n++)
          acc[m][n] = __builtin_amdgcn_mfma_f32_16x16x32_bf16(af[m], bfm[n], acc[m][n], 0,0,0);
    }
  };

  int nt = K >> 6;
  STAGE(As0, Bs0, 0);
  for (int t=0; t<nt-2; t+=2){
    STAGE(As1, Bs1, (t+1)*64);
    asm volatile("s_waitcnt vmcnt(8)" ::: "memory");
    __builtin_amdgcn_s_barrier();
    COMPUTE(As0, Bs0);
    __builtin_amdgcn_s_barrier();
    STAGE(As0, Bs0, (t+2)*64);
    asm volatile("s_waitcnt vmcnt(8)" ::: "memory");
    __builtin_amdgcn_s_barrier();
    COMPUTE(As1, Bs1);
    __builtin_amdgcn_s_barrier();
  }
  STAGE(As1, Bs1, (nt-1)*64);
  asm volatile("s_waitcnt vmcnt(8)" ::: "memory");
  __builtin_amdgcn_s_barrier();
  COMPUTE(As0, Bs0);
  asm volatile("s_waitcnt vmcnt(0)" ::: "memory");
  __builtin_amdgcn_s_barrier();
  COMPUTE(As1, Bs1);

  int rl = (lane>>4)<<2;
  #pragma unroll
  for (int m=0;m<4;m++){
    #pragma unroll
    for (int n=0;n<4;n++){
      int gc = col0 + wc*64 + n*16 + (lane&15);
      #pragma unroll
      for (int r=0;r<4;r++){
        size_t gi = (size_t)(row0 + wr*64 + m*16 + rl + r)*ldc + gc;
        if constexpr (EPI) Cf[gi] = acc[m][n][r] + resid[gi];
        else               C[gi]  = f2bf(acc[m][n][r]);
      }
    }
  }
}

// ---------------- kv_state with FUSED feature map, split-K=8 ----------------
__global__ __launch_bounds__(256) void k_kvstate(const u16* __restrict__ kvb,
    const u16* __restrict__ WkfT, float* __restrict__ part){
  const int P = 76;
  __shared__ u16 kc[64*64];
  __shared__ u16 wb[16*72];
  __shared__ float fL[64*16];
  __shared__ u16 ph[160*P];
  __shared__ u16 vt[80*P];
  int bh = blockIdx.x, b = bh>>4, h = bh&15;
  int ks = blockIdx.y;
  int tid = threadIdx.x, lane = tid&63, w = tid>>6;
  int srow = lane>>3;
  int scb  = ((lane&7)*16) ^ (srow<<4);
  for (int i=tid;i<1024;i+=256) wb[(i>>6)*72 + (i&63)] = WkfT[i];
  for (int i=tid; i<16*P; i+=256){
    int r = 64 + i/P, c = i - (i/P)*P;
    vt[r*P + c] = (r==64) ? (u16)0x3F80 : (u16)0;
  }
  f32x4 acc[5][3] = {};
  for (int c=0;c<4;c++){
    int s0 = ks*256 + c*64;
    __syncthreads();
    #pragma unroll
    for (int i=0;i<2;i++){
      int ch = w + i*4;
      int r = ch*8 + srow;
      gload_lds16((const char*)(kvb + (size_t)(b*TSEQ + s0 + r)*2048 + h*HD) + scb,
                  (char*)kc + ch*1024);
    }
    for (int s = w; s < 64; s += 4)
      vt[lane*P + s] = kvb[(size_t)(b*TSEQ + s0 + s)*2048 + 1024 + h*HD + lane];
    __syncthreads();
    {
      f32x4 fa = {};
      #pragma unroll
      for (int kk=0;kk<2;kk++){
        int bc = 2*(kk*32 + ((lane>>4)<<3));
        int r = w*16 + (lane&15);
        bf16x8 av = *(const bf16x8*)((const char*)kc + r*128 + (bc ^ ((r&7)<<4)));
        bf16x8 bv = *(const bf16x8*)(wb + (lane&15)*72 + kk*32 + ((lane>>4)<<3));
        fa = __builtin_amdgcn_mfma_f32_16x16x32_bf16(av, bv, fa, 0,0,0);
      }
      int rl = (lane>>4)<<2;
      #pragma unroll
      for (int r=0;r<4;r++) fL[(w*16 + rl + r)*16 + (lane&15)] = fa[r];
    }
    __syncthreads();
    {
      int r = tid>>2, jq = tid&3;
      float4 v0 = *(const float4*)(fL + r*16 + 0);
      float4 v1 = *(const float4*)(fL + r*16 + 4);
      float4 v2 = *(const float4*)(fL + r*16 + 8);
      float4 v3 = *(const float4*)(fL + r*16 + 12);
      float f[16] = {v0.x,v0.y,v0.z,v0.w, v1.x,v1.y,v1.z,v1.w,
                     v2.x,v2.y,v2.z,v2.w, v3.x,v3.y,v3.z,v3.w};
      if ((0&3)==jq) ph[0*P + r] = 0x3F80;
      #pragma unroll
      for (int q=0;q<16;q++) if (((1+q)&3)==jq) ph[(1+q)*P + r] = f2bf(f[q]);
      int pos = 17;
      #pragma unroll
      for (int i=0;i<16;i++)
        #pragma unroll
        for (int j=i;j<16;j++){
          if ((pos&3)==jq) ph[pos*P + r] = f2bf(f[i]*f[j]*((i==j)?0.5f:RS2));
          pos++;
        }
      #pragma unroll
      for (int z=153;z<160;z++) if ((z&3)==jq) ph[z*P + r] = 0;
    }
    __syncthreads();
    #pragma unroll
    for (int kk=0;kk<2;kk++){
      int lk = kk*32 + ((lane>>4)<<3);
      bf16x8 bfr[3];
      #pragma unroll
      for (int nn=0;nn<3;nn++){
        int ncol = (nn<2) ? (w*2+nn) : (8+(w&1));
        bfr[nn] = *(const bf16x8*)(ph + (ncol*16 + (lane&15))*P + lk);
      }
      #pragma unroll
      for (int m=0;m<5;m++){
        bf16x8 av = *(const bf16x8*)(vt + (m*16 + (lane&15))*P + lk);
        #pragma unroll
        for (int nn=0;nn<3;nn++)
          acc[m][nn] = __builtin_amdgcn_mfma_f32_16x16x32_bf16(av, bfr[nn], acc[m][nn], 0,0,0);
      }
    }
  }
  int rl = (lane>>4)<<2;
  float* pp = part + ((size_t)ks*32 + bh)*80*160;
  #pragma unroll
  for (int m=0;m<5;m++){
    #pragma unroll
    for (int nn=0;nn<3;nn++){
      int ncol = (nn<2) ? (w*2+nn) : (8+(w&1));
      if (nn==2 && w>=2) continue;
      int fcol = ncol*16 + (lane&15);
      #pragma unroll
      for (int r=0;r<4;r++)
        pp[(size_t)(m*16 + rl + r)*160 + fcol] = acc[m][nn][r];
    }
  }
}

// ---------------- reduce split-K partials -> kvsT bf16 [bh][80][160] ----------------
__global__ __launch_bounds__(256) void k_kvreduce(const float* __restrict__ part,
    u16* __restrict__ kvsT){
  int i = blockIdx.x*256 + threadIdx.x;
  float s = 0.f;
  #pragma unroll
  for (int c=0;c<KSPLIT;c++) s += part[(size_t)c*409600 + i];
  kvsT[i] = f2bf(s);
}

// ---------------- linear attention with FUSED feature map ----------------
__global__ __launch_bounds__(256) void k_linattn(const u16* __restrict__ qwin,
    const u16* __restrict__ WqfT, const u16* __restrict__ kvsT, u16* __restrict__ comb){
  const int LS = 168;
  __shared__ u16 As[64*LS];
  __shared__ u16 Bs[80*LS];
  __shared__ u16 qc[64*64];
  __shared__ u16 wb[16*72];
  __shared__ float fL[64*16];
  int bh = blockIdx.x, b = bh>>4, h = bh&15;
  int t0 = blockIdx.y*64;
  int tid = threadIdx.x, lane = tid&63, wid = tid>>6;
  int srow = lane>>3;
  int scb  = ((lane&7)*16) ^ (srow<<4);
  for (int i=tid;i<1024;i+=256) wb[(i>>6)*72 + (i&63)] = WqfT[i];
  for (int i=tid*8; i<80*FPAD; i+=2048){
    int r = i/FPAD, ff = i - r*FPAD;
    *(bf16x8*)(Bs + r*LS + ff) = *(const bf16x8*)(kvsT + (size_t)bh*80*FPAD + i);
  }
  #pragma unroll
  for (int i=0;i<2;i++){
    int ch = wid + i*4;
    int r = ch*8 + srow;
    gload_lds16((const char*)(qwin + (size_t)(b*TSEQ + t0 + r)*3072 + h*HD) + scb,
                (char*)qc + ch*1024);
  }
  __syncthreads();
  {
    f32x4 fa = {};
    #pragma unroll
    for (int kk=0;kk<2;kk++){
      int bc = 2*(kk*32 + ((lane>>4)<<3));
      int r = wid*16 + (lane&15);
      bf16x8 av = *(const bf16x8*)((const char*)qc + r*128 + (bc ^ ((r&7)<<4)));
      bf16x8 bv = *(const bf16x8*)(wb + (lane&15)*72 + kk*32 + ((lane>>4)<<3));
      fa = __builtin_amdgcn_mfma_f32_16x16x32_bf16(av, bv, fa, 0,0,0);
    }
    int rl = (lane>>4)<<2;
    #pragma unroll
    for (int r=0;r<4;r++) fL[(wid*16 + rl + r)*16 + (lane&15)] = fa[r];
  }
  __syncthreads();
  {
    int r = tid>>2, jq = tid&3;
    float4 v0 = *(const float4*)(fL + r*16 + 0);
    float4 v1 = *(const float4*)(fL + r*16 + 4);
    float4 v2 = *(const float4*)(fL + r*16 + 8);
    float4 v3 = *(const float4*)(fL + r*16 + 12);
    float f[16] = {v0.x,v0.y,v0.z,v0.w, v1.x,v1.y,v1.z,v1.w,
                   v2.x,v2.y,v2.z,v2.w, v3.x,v3.y,v3.z,v3.w};
    if ((0&3)==jq) As[r*LS + 0] = 0x3F80;
    #pragma unroll
    for (int q=0;q<16;q++) if (((1+q)&3)==jq) As[r*LS + 1+q] = f2bf(f[q]);
    int pos = 17;
    #pragma unroll
    for (int i=0;i<16;i++)
      #pragma unroll
      for (int j=i;j<16;j++){
        if ((pos&3)==jq) As[r*LS + pos] = f2bf(f[i]*f[j]*((i==j)?0.5f:RS2));
        pos++;
      }
    #pragma unroll
    for (int z=153;z<160;z++) if ((z&3)==jq) As[r*LS + z] = 0;
  }
  __syncthreads();
  f32x4 acc[5] = {};
  #pragma unroll
  for (int ks=0;ks<5;ks++){
    int lk = ks*32 + ((lane>>4)<<3);
    bf16x8 a = *(const bf16x8*)(As + (wid*16 + (lane&15))*LS + lk);
    #pragma unroll
    for (int n=0;n<5;n++){
      bf16x8 bb = *(const bf16x8*)(Bs + (n*16 + (lane&15))*LS + lk);
      acc[n] = __builtin_amdgcn_mfma_f32_16x16x32_bf16(a, bb, acc[n], 0,0,0);
    }
  }
  int rl = (lane>>4)<<2;
  #pragma unroll
  for (int r=0;r<4;r++){
    float nrm = __shfl(acc[4][r], lane & 48) + 1e-6f;
    float inv = 1.0f / nrm;
    int t = t0 + wid*16 + rl + r;
    #pragma unroll
    for (int n=0;n<4;n++){
      comb[(size_t)(b*TSEQ + t)*2048 + h*64 + n*16 + (lane&15)] = f2bf(acc[n][r]*inv);
    }
  }
}

// ---------------- sliding-window attention (window = 65 incl. self) ----------------
__global__ __launch_bounds__(256) void k_window(const u16* __restrict__ q, int ldq,
    const u16* __restrict__ kvwin, int ldkv, u16* __restrict__ comb){
  const int LQ = 72, LV = 136;
  __shared__ u16 q_s [64*LQ];
  __shared__ u16 k_s [128*LQ];
  __shared__ u16 vT_s[64*LV];
  __shared__ u16 p_s [64*LV];
  int bh = blockIdx.x, b = bh>>4, h = bh&15;
  int t0 = blockIdx.y*64;
  int tid = threadIdx.x, lane = tid&63, wid = tid>>6;
  int j0 = t0 - 64;
  bf16x8 zv = {0,0,0,0,0,0,0,0};
  for (int cc=tid; cc<512; cc+=256){
    int r = cc>>3, c8 = cc&7;
    *(bf16x8*)(q_s + r*LQ + c8*8) =
      *(const bf16x8*)(q + (size_t)(b*TSEQ + t0 + r)*ldq + h*HD + c8*8);
  }
  for (int cc=tid; cc<1024; cc+=256){
    int r = cc>>3, c8 = cc&7;
    int j = j0 + r;
    bf16x8 kv8 = (j>=0) ? *(const bf16x8*)(kvwin + (size_t)(b*TSEQ + j)*ldkv + h*HD + c8*8) : zv;
    *(bf16x8*)(k_s + r*LQ + c8*8) = kv8;
    bf16x8 vv8 = (j>=0) ? *(const bf16x8*)(kvwin + (size_t)(b*TSEQ + j)*ldkv + 1024 + h*HD + c8*8) : zv;
    #pragma unroll
    for (int e=0;e<8;e++) vT_s[(c8*8+e)*LV + r] = (u16)vv8[e];
  }
  __syncthreads();
  f32x4 sa[8] = {};
  #pragma unroll
  for (int kk=0;kk<64;kk+=32){
    int lk = kk + ((lane>>4)<<3);
    bf16x8 a = *(const bf16x8*)(q_s + (wid*16 + (lane&15))*LQ + lk);
    #pragma unroll
    for (int n=0;n<8;n++){
      bf16x8 bb = *(const bf16x8*)(k_s + (n*16 + (lane&15))*LQ + lk);
      sa[n] = __builtin_amdgcn_mfma_f32_16x16x32_bf16(a, bb, sa[n], 0,0,0);
    }
  }
  int rl = (lane>>4)<<2;
  float pr[8][4];
  #pragma unroll
  for (int r=0;r<4;r++){
    int ig = t0 + wid*16 + rl + r;
    float mx = -1e30f;
    float sv[8];
    #pragma unroll
    for (int n=0;n<8;n++){
      int jg = j0 + n*16 + (lane&15);
      float s = sa[n][r]*0.125f;
      bool ok = (jg>=0) && (jg<=ig) && (jg>=ig-WIN);
      s = ok ? s : -1e30f;
      sv[n]=s; mx = fmaxf(mx, s);
    }
    #pragma unroll
    for (int m=1;m<16;m<<=1) mx = fmaxf(mx, __shfl_xor(mx, m));
    float sum = 0.f;
    #pragma unroll
    for (int n=0;n<8;n++){ float e = __expf(sv[n]-mx); sv[n]=e; sum += e; }
    #pragma unroll
    for (int m=1;m<16;m<<=1) sum += __shfl_xor(sum, m);
    float inv = 1.0f/sum;
    #pragma unroll
    for (int n=0;n<8;n++) pr[n][r] = sv[n]*inv;
  }
  #pragma unroll
  for (int n=0;n<8;n++)
    #pragma unroll
    for (int r=0;r<4;r++)
      p_s[(wid*16 + rl + r)*LV + n*16 + (lane&15)] = f2bf(pr[n][r]);
  __syncthreads();
  f32x4 oa[4] = {};
  #pragma unroll
  for (int ks=0;ks<4;ks++){
    int lk = ks*32 + ((lane>>4)<<3);
    bf16x8 a = *(const bf16x8*)(p_s + (wid*16 + (lane&15))*LV + lk);
    #pragma unroll
    for (int n=0;n<4;n++){
      bf16x8 bb = *(const bf16x8*)(vT_s + (n*16 + (lane&15))*LV + lk);
      oa[n] = __builtin_amdgcn_mfma_f32_16x16x32_bf16(a, bb, oa[n], 0,0,0);
    }
  }
  #pragma unroll
  for (int n=0;n<4;n++)
    #pragma unroll
    for (int r=0;r<4;r++)
      comb[(size_t)(b*TSEQ + t0 + wid*16 + rl + r)*2048 + 1024 + h*HD + n*16 + (lane&15)]
        = f2bf(oa[n][r]);
}

extern "C" void kernel_launch(void* const* d_in, const int* in_sizes, int n_in,
                              void* d_out, int out_size, void* d_ws, size_t ws_size,
                              hipStream_t stream){
  (void)in_sizes; (void)n_in; (void)out_size; (void)ws_size;
  const float* x    = (const float*)d_in[0];
  const float* enc  = (const float*)d_in[1];
  const float* nw   = (const float*)d_in[2];
  const float* Wq   = (const float*)d_in[3];
  const float* Wkv  = (const float*)d_in[4];
  const float* Wqf  = (const float*)d_in[5];
  const float* Wkf  = (const float*)d_in[6];
  const float* Wwin = (const float*)d_in[7];
  const float* Wout = (const float*)d_in[8];
  float* out = (float*)d_out;

  char* p = (char*)d_ws;
  auto alloc = [&](size_t bytes)->char*{
    char* r = p; p += (bytes + 255) & ~(size_t)255; return r;
  };
  // part (13.1 MB f32) aliases [xn, encb] (16.8 MB) — both dead before k_kvstate.
  char*  aliasBase = p;
  u16*   xn    = (u16*)  alloc((size_t)ROWS*DM*2);
  u16*   encb  = (u16*)  alloc((size_t)ROWS*DM*2);
  u16*   WqwT  = (u16*)  alloc((size_t)3072*DM*2);   // rows 0..1023 Wq^T, 1024..3071 Wwin^T
  u16*   WkvT  = (u16*)  alloc((size_t)2048*DM*2);
  float* part  = (float*)aliasBase;
  u16*   WoutT = (u16*)  alloc((size_t)DM*2048*2);
  u16*   WqfT  = (u16*)  alloc((size_t)FD*HD*2);
  u16*   WkfT  = (u16*)  alloc((size_t)FD*HD*2);
  u16*   qwin  = (u16*)  alloc((size_t)ROWS*3072*2); // [q | k_win | v_win], ld 3072
  u16*   kvb   = (u16*)  alloc((size_t)ROWS*2048*2);
  u16*   kvsT  = (u16*)  alloc((size_t)32*80*FPAD*2);
  u16*   comb  = (u16*)  alloc((size_t)ROWS*2048*2);

  k_prep <<<dim3(ROWS, 2), 256, 0, stream>>>(x, enc, nw, xn, encb);
  k_packw<<<7170, 256, 0, stream>>>(Wq, Wwin, Wkv, Wout, Wqf, Wkf,
                                    WqwT, WkvT, WoutT, WqfT, WkfT);

  k_gemm<0><<<dim3(ROWS/128, 40), 256, 0, stream>>>(
      xn, WqwT, qwin, 3072,  encb, WkvT, kvb, 2048,  24, DM, nullptr, nullptr);

  k_kvstate<<<dim3(32, KSPLIT), 256, 0, stream>>>(kvb, WkfT, part);
  k_kvreduce<<<1600, 256, 0, stream>>>(part, kvsT);

  k_linattn<<<dim3(32, TSEQ/64), 256, 0, stream>>>(qwin, WqfT, kvsT, comb);
  k_window <<<dim3(32, TSEQ/64), 256, 0, stream>>>(qwin, 3072, qwin + 1024, 3072, comb);

  k_gemm<1><<<dim3(ROWS/128, 8), 256, 0, stream>>>(
      comb, WoutT, nullptr, DM,  nullptr, nullptr, nullptr, 0,  8, 2048, out, x);
}

// Round 6
// 162.780 us; speedup vs baseline: 2.3178x; 1.0516x over previous
//
#include <hip/hip_runtime.h>

#define DM 1024
#define NH 16
#define HD 64
#define FD 16
#define NF 153
#define FPAD 160
#define WIN 64
#define TSEQ 2048
#define ROWS 4096
#define KSPLIT 8
#define RS2 0.70710678118654752f

typedef unsigned short u16;
typedef __attribute__((ext_vector_type(8))) short bf16x8;
typedef __attribute__((ext_vector_type(8))) unsigned short u16x8;
typedef __attribute__((ext_vector_type(4))) unsigned short u16x4;
typedef __attribute__((ext_vector_type(4))) float f32x4;

#define GLB_AS __attribute__((address_space(1)))
#define LDS_AS __attribute__((address_space(3)))

static __device__ __forceinline__ void gload_lds16(const void* g, void* l){
  __builtin_amdgcn_global_load_lds((const GLB_AS void*)g, (LDS_AS void*)l, 16, 0, 0);
}

static __device__ __forceinline__ float bf2f(u16 u){
  unsigned v = ((unsigned)u) << 16;
  return __builtin_bit_cast(float, v);
}
static __device__ __forceinline__ u16 f2bf(float f){
  unsigned u = __builtin_bit_cast(unsigned, f);
  u += 0x7FFFu + ((u >> 16) & 1u);
  return (u16)(u >> 16);
}

// ---------------- prep (rmsnorm + enc cast) AND weight packing, one dispatch ----------------
static __device__ __forceinline__ void tr_tile(const float* __restrict__ in,
    u16* __restrict__ out, int K, int N, int n0, int k0, float* t, int tid){
  int tx = tid & 31, ty = tid >> 5;
  #pragma unroll
  for (int i=0;i<4;i++) t[(ty + i*8)*33 + tx] = in[(size_t)(k0 + ty + i*8)*N + n0 + tx];
  __syncthreads();
  #pragma unroll
  for (int i=0;i<4;i++) out[(size_t)(n0 + ty + i*8)*K + k0 + tx] = f2bf(t[tx*33 + ty + i*8]);
}

__global__ __launch_bounds__(256) void k_prep(const float* __restrict__ x,
    const float* __restrict__ enc, const float* __restrict__ w,
    const float* __restrict__ Wq, const float* __restrict__ Wwin,
    const float* __restrict__ Wkv, const float* __restrict__ Wout,
    const float* __restrict__ Wqf, const float* __restrict__ Wkf,
    u16* __restrict__ xn, u16* __restrict__ encb,
    u16* __restrict__ WqwT, u16* __restrict__ WkvT, u16* __restrict__ WoutT,
    u16* __restrict__ WqfT, u16* __restrict__ WkfT){
  __shared__ float t[32*33];
  int bx = blockIdx.x, tid = threadIdx.x;
  if (bx < ROWS){
    int row = bx;
    const float4* xr = (const float4*)(x + (size_t)row*DM);
    float4 a = xr[tid];
    float ss = a.x*a.x + a.y*a.y + a.z*a.z + a.w*a.w;
    #pragma unroll
    for (int m=1;m<64;m<<=1) ss += __shfl_xor(ss, m);
    __shared__ float red[4];
    if ((tid&63)==0) red[tid>>6] = ss;
    __syncthreads();
    float tot = red[0]+red[1]+red[2]+red[3];
    float rs = rsqrtf(tot*(1.0f/DM) + 1e-6f);
    float4 wv = ((const float4*)w)[tid];
    u16x4 o;
    o[0]=f2bf(a.x*rs*wv.x); o[1]=f2bf(a.y*rs*wv.y);
    o[2]=f2bf(a.z*rs*wv.z); o[3]=f2bf(a.w*rs*wv.w);
    ((u16x4*)(xn + (size_t)row*DM))[tid] = o;
  } else if (bx < 2*ROWS){
    int row = bx - ROWS;
    float4 a = ((const float4*)(enc + (size_t)row*DM))[tid];
    u16x4 o;
    o[0]=f2bf(a.x); o[1]=f2bf(a.y); o[2]=f2bf(a.z); o[3]=f2bf(a.w);
    ((u16x4*)(encb + (size_t)row*DM))[tid] = o;
  } else {
    int b = bx - 2*ROWS;
    if (b < 1024){
      tr_tile(Wq, WqwT, 1024, 1024, (b&31)*32, (b>>5)*32, t, tid);
    } else if (b < 3072){
      int r = b-1024;
      tr_tile(Wwin, WqwT + (size_t)1024*1024, 1024, 2048, (r&63)*32, (r>>6)*32, t, tid);
    } else if (b < 5120){
      int r = b-3072;
      tr_tile(Wkv, WkvT, 1024, 2048, (r&63)*32, (r>>6)*32, t, tid);
    } else if (b < 7168){
      int r = b-5120;
      tr_tile(Wout, WoutT, 2048, 1024, (r&31)*32, (r>>5)*32, t, tid);
    } else {
      const float* src = (b==7168) ? Wqf : Wkf;
      u16* dst = (b==7168) ? WqfT : WkfT;
      for (int i=tid;i<1024;i+=256) dst[i] = f2bf(src[(i&63)*16 + (i>>6)]);
    }
  }
}

// ---------------- batched pipelined GEMM: 512 threads, 8 waves, wave tile 64x32 ----------------
// 128x128 tile, BK=64, dbuf LDS (64KB -> 2 blocks/CU = 16 waves/CU), counted vmcnt(4).
template<int EPI>
__global__ __launch_bounds__(512) void k_gemm(
    const u16* __restrict__ A0, const u16* __restrict__ B0, u16* __restrict__ C0, int ldc0,
    const u16* __restrict__ A1, const u16* __restrict__ B1, u16* __restrict__ C1, int ldc1,
    int split, int K, float* __restrict__ Cf, const float* __restrict__ resid){
  __shared__ u16 As0[128*64];
  __shared__ u16 Bs0[128*64];
  __shared__ u16 As1[128*64];
  __shared__ u16 Bs1[128*64];
  int by = blockIdx.y;
  const u16 *A, *Bt; u16* C; int ldc;
  if (by < split){ A=A0; Bt=B0; C=C0; ldc=ldc0; }
  else { by -= split; A=A1; Bt=B1; C=C1; ldc=ldc1; }
  int row0 = blockIdx.x*128, col0 = by*128;
  int tid = threadIdx.x, lane = tid&63, wid = tid>>6;
  int wm = wid>>2, wn = wid&3;           // wave tile: rows [wm*64, +64), cols [wn*32, +32)
  int srow = lane>>3;
  int scb  = ((lane&7)*16) ^ (srow<<4);  // inverse-swizzled source byte col (involution)
  f32x4 acc[4][2] = {};

  auto STAGE = [&](u16* Asb, u16* Bsb, int k0){
    #pragma unroll
    for (int i=0;i<2;i++){
      int chunk = wid*2 + i;             // 16 chunks of 8 rows each
      int r = chunk*8 + srow;
      gload_lds16((const char*)(A  + (size_t)(row0+r)*K + k0) + scb, (char*)Asb + chunk*1024);
      gload_lds16((const char*)(Bt + (size_t)(col0+r)*K + k0) + scb, (char*)Bsb + chunk*1024);
    }
  };
  auto COMPUTE = [&](const u16* Asb, const u16* Bsb){
    #pragma unroll
    for (int kk=0;kk<64;kk+=32){
      int bc = 2*(kk + ((lane>>4)<<3));
      bf16x8 af[4], bfm[2];
      #pragma unroll
      for (int m=0;m<4;m++){
        int r = wm*64 + m*16 + (lane&15);
        af[m]  = *(const bf16x8*)((const char*)Asb + r*128 + (bc ^ ((r&7)<<4)));
      }
      #pragma unroll
      for (int n=0;n<2;n++){
        int r = wn*32 + n*16 + (lane&15);
        bfm[n] = *(const bf16x8*)((const char*)Bsb + r*128 + (bc ^ ((r&7)<<4)));
      }
      #pragma unroll
      for (int m=0;m<4;m++)
        #pragma unroll
        for (int n=0;n<2;n++)
          acc[m][n] = __builtin_amdgcn_mfma_f32_16x16x32_bf16(af[m], bfm[n], acc[m][n], 0,0,0);
    }
  };

  int nt = K >> 6;                       // even (16 or 32)
  STAGE(As0, Bs0, 0);
  for (int t=0; t<nt-2; t+=2){
    STAGE(As1, Bs1, (t+1)*64);
    asm volatile("s_waitcnt vmcnt(4)" ::: "memory");
    __builtin_amdgcn_s_barrier();
    COMPUTE(As0, Bs0);
    __builtin_amdgcn_s_barrier();
    STAGE(As0, Bs0, (t+2)*64);
    asm volatile("s_waitcnt vmcnt(4)" ::: "memory");
    __builtin_amdgcn_s_barrier();
    COMPUTE(As1, Bs1);
    __builtin_amdgcn_s_barrier();
  }
  STAGE(As1, Bs1, (nt-1)*64);
  asm volatile("s_waitcnt vmcnt(4)" ::: "memory");
  __builtin_amdgcn_s_barrier();
  COMPUTE(As0, Bs0);
  asm volatile("s_waitcnt vmcnt(0)" ::: "memory");
  __builtin_amdgcn_s_barrier();
  COMPUTE(As1, Bs1);

  int rl = (lane>>4)<<2;
  #pragma unroll
  for (int m=0;m<4;m++){
    #pragma unroll
    for (int n=0;n<2;n++){
      int gc = col0 + wn*32 + n*16 + (lane&15);
      #pragma unroll
      for (int r=0;r<4;r++){
        size_t gi = (size_t)(row0 + wm*64 + m*16 + rl + r)*ldc + gc;
        if constexpr (EPI) Cf[gi] = acc[m][n][r] + resid[gi];
        else               C[gi]  = f2bf(acc[m][n][r]);
      }
    }
  }
}

// ---------------- kv_state with FUSED feature map, split-K=8 ----------------
__global__ __launch_bounds__(256) void k_kvstate(const u16* __restrict__ kvb,
    const u16* __restrict__ WkfT, float* __restrict__ part){
  const int P = 76;
  __shared__ u16 kc[64*64];
  __shared__ u16 wb[16*72];
  __shared__ float fL[64*16];
  __shared__ u16 ph[160*P];
  __shared__ u16 vt[80*P];
  int bh = blockIdx.x, b = bh>>4, h = bh&15;
  int ks = blockIdx.y;
  int tid = threadIdx.x, lane = tid&63, w = tid>>6;
  int srow = lane>>3;
  int scb  = ((lane&7)*16) ^ (srow<<4);
  for (int i=tid;i<1024;i+=256) wb[(i>>6)*72 + (i&63)] = WkfT[i];
  for (int i=tid; i<16*P; i+=256){
    int r = 64 + i/P, c = i - (i/P)*P;
    vt[r*P + c] = (r==64) ? (u16)0x3F80 : (u16)0;
  }
  f32x4 acc[5][3] = {};
  for (int c=0;c<4;c++){
    int s0 = ks*256 + c*64;
    __syncthreads();
    #pragma unroll
    for (int i=0;i<2;i++){
      int ch = w + i*4;
      int r = ch*8 + srow;
      gload_lds16((const char*)(kvb + (size_t)(b*TSEQ + s0 + r)*2048 + h*HD) + scb,
                  (char*)kc + ch*1024);
    }
    for (int s = w; s < 64; s += 4)
      vt[lane*P + s] = kvb[(size_t)(b*TSEQ + s0 + s)*2048 + 1024 + h*HD + lane];
    __syncthreads();
    {
      f32x4 fa = {};
      #pragma unroll
      for (int kk=0;kk<2;kk++){
        int bc = 2*(kk*32 + ((lane>>4)<<3));
        int r = w*16 + (lane&15);
        bf16x8 av = *(const bf16x8*)((const char*)kc + r*128 + (bc ^ ((r&7)<<4)));
        bf16x8 bv = *(const bf16x8*)(wb + (lane&15)*72 + kk*32 + ((lane>>4)<<3));
        fa = __builtin_amdgcn_mfma_f32_16x16x32_bf16(av, bv, fa, 0,0,0);
      }
      int rl = (lane>>4)<<2;
      #pragma unroll
      for (int r=0;r<4;r++) fL[(w*16 + rl + r)*16 + (lane&15)] = fa[r];
    }
    __syncthreads();
    {
      int r = tid>>2, jq = tid&3;
      float4 v0 = *(const float4*)(fL + r*16 + 0);
      float4 v1 = *(const float4*)(fL + r*16 + 4);
      float4 v2 = *(const float4*)(fL + r*16 + 8);
      float4 v3 = *(const float4*)(fL + r*16 + 12);
      float f[16] = {v0.x,v0.y,v0.z,v0.w, v1.x,v1.y,v1.z,v1.w,
                     v2.x,v2.y,v2.z,v2.w, v3.x,v3.y,v3.z,v3.w};
      if ((0&3)==jq) ph[0*P + r] = 0x3F80;
      #pragma unroll
      for (int q=0;q<16;q++) if (((1+q)&3)==jq) ph[(1+q)*P + r] = f2bf(f[q]);
      int pos = 17;
      #pragma unroll
      for (int i=0;i<16;i++)
        #pragma unroll
        for (int j=i;j<16;j++){
          if ((pos&3)==jq) ph[pos*P + r] = f2bf(f[i]*f[j]*((i==j)?0.5f:RS2));
          pos++;
        }
      #pragma unroll
      for (int z=153;z<160;z++) if ((z&3)==jq) ph[z*P + r] = 0;
    }
    __syncthreads();
    #pragma unroll
    for (int kk=0;kk<2;kk++){
      int lk = kk*32 + ((lane>>4)<<3);
      bf16x8 bfr[3];
      #pragma unroll
      for (int nn=0;nn<3;nn++){
        int ncol = (nn<2) ? (w*2+nn) : (8+(w&1));
        bfr[nn] = *(const bf16x8*)(ph + (ncol*16 + (lane&15))*P + lk);
      }
      #pragma unroll
      for (int m=0;m<5;m++){
        bf16x8 av = *(const bf16x8*)(vt + (m*16 + (lane&15))*P + lk);
        #pragma unroll
        for (int nn=0;nn<3;nn++)
          acc[m][nn] = __builtin_amdgcn_mfma_f32_16x16x32_bf16(av, bfr[nn], acc[m][nn], 0,0,0);
      }
    }
  }
  int rl = (lane>>4)<<2;
  float* pp = part + ((size_t)ks*32 + bh)*80*160;
  #pragma unroll
  for (int m=0;m<5;m++){
    #pragma unroll
    for (int nn=0;nn<3;nn++){
      int ncol = (nn<2) ? (w*2+nn) : (8+(w&1));
      if (nn==2 && w>=2) continue;
      int fcol = ncol*16 + (lane&15);
      #pragma unroll
      for (int r=0;r<4;r++)
        pp[(size_t)(m*16 + rl + r)*160 + fcol] = acc[m][nn][r];
    }
  }
}

// ---------------- reduce split-K partials -> kvsT bf16 [bh][80][160] ----------------
__global__ __launch_bounds__(256) void k_kvreduce(const float* __restrict__ part,
    u16* __restrict__ kvsT){
  int i = blockIdx.x*256 + threadIdx.x;
  float s = 0.f;
  #pragma unroll
  for (int c=0;c<KSPLIT;c++) s += part[(size_t)c*409600 + i];
  kvsT[i] = f2bf(s);
}

// ---------------- linear attention with FUSED feature map ----------------
__global__ __launch_bounds__(256) void k_linattn(const u16* __restrict__ qwin,
    const u16* __restrict__ WqfT, const u16* __restrict__ kvsT, u16* __restrict__ comb){
  const int LS = 168;
  __shared__ u16 As[64*LS];
  __shared__ u16 Bs[80*LS];
  __shared__ u16 qc[64*64];
  __shared__ u16 wb[16*72];
  __shared__ float fL[64*16];
  int bh = blockIdx.x, b = bh>>4, h = bh&15;
  int t0 = blockIdx.y*64;
  int tid = threadIdx.x, lane = tid&63, wid = tid>>6;
  int srow = lane>>3;
  int scb  = ((lane&7)*16) ^ (srow<<4);
  for (int i=tid;i<1024;i+=256) wb[(i>>6)*72 + (i&63)] = WqfT[i];
  for (int i=tid*8; i<80*FPAD; i+=2048){
    int r = i/FPAD, ff = i - r*FPAD;
    *(bf16x8*)(Bs + r*LS + ff) = *(const bf16x8*)(kvsT + (size_t)bh*80*FPAD + i);
  }
  #pragma unroll
  for (int i=0;i<2;i++){
    int ch = wid + i*4;
    int r = ch*8 + srow;
    gload_lds16((const char*)(qwin + (size_t)(b*TSEQ + t0 + r)*3072 + h*HD) + scb,
                (char*)qc + ch*1024);
  }
  __syncthreads();
  {
    f32x4 fa = {};
    #pragma unroll
    for (int kk=0;kk<2;kk++){
      int bc = 2*(kk*32 + ((lane>>4)<<3));
      int r = wid*16 + (lane&15);
      bf16x8 av = *(const bf16x8*)((const char*)qc + r*128 + (bc ^ ((r&7)<<4)));
      bf16x8 bv = *(const bf16x8*)(wb + (lane&15)*72 + kk*32 + ((lane>>4)<<3));
      fa = __builtin_amdgcn_mfma_f32_16x16x32_bf16(av, bv, fa, 0,0,0);
    }
    int rl = (lane>>4)<<2;
    #pragma unroll
    for (int r=0;r<4;r++) fL[(wid*16 + rl + r)*16 + (lane&15)] = fa[r];
  }
  __syncthreads();
  {
    int r = tid>>2, jq = tid&3;
    float4 v0 = *(const float4*)(fL + r*16 + 0);
    float4 v1 = *(const float4*)(fL + r*16 + 4);
    float4 v2 = *(const float4*)(fL + r*16 + 8);
    float4 v3 = *(const float4*)(fL + r*16 + 12);
    float f[16] = {v0.x,v0.y,v0.z,v0.w, v1.x,v1.y,v1.z,v1.w,
                   v2.x,v2.y,v2.z,v2.w, v3.x,v3.y,v3.z,v3.w};
    if ((0&3)==jq) As[r*LS + 0] = 0x3F80;
    #pragma unroll
    for (int q=0;q<16;q++) if (((1+q)&3)==jq) As[r*LS + 1+q] = f2bf(f[q]);
    int pos = 17;
    #pragma unroll
    for (int i=0;i<16;i++)
      #pragma unroll
      for (int j=i;j<16;j++){
        if ((pos&3)==jq) As[r*LS + pos] = f2bf(f[i]*f[j]*((i==j)?0.5f:RS2));
        pos++;
      }
    #pragma unroll
    for (int z=153;z<160;z++) if ((z&3)==jq) As[r*LS + z] = 0;
  }
  __syncthreads();
  f32x4 acc[5] = {};
  #pragma unroll
  for (int ks=0;ks<5;ks++){
    int lk = ks*32 + ((lane>>4)<<3);
    bf16x8 a = *(const bf16x8*)(As + (wid*16 + (lane&15))*LS + lk);
    #pragma unroll
    for (int n=0;n<5;n++){
      bf16x8 bb = *(const bf16x8*)(Bs + (n*16 + (lane&15))*LS + lk);
      acc[n] = __builtin_amdgcn_mfma_f32_16x16x32_bf16(a, bb, acc[n], 0,0,0);
    }
  }
  int rl = (lane>>4)<<2;
  #pragma unroll
  for (int r=0;r<4;r++){
    float nrm = __shfl(acc[4][r], lane & 48) + 1e-6f;
    float inv = 1.0f / nrm;
    int t = t0 + wid*16 + rl + r;
    #pragma unroll
    for (int n=0;n<4;n++){
      comb[(size_t)(b*TSEQ + t)*2048 + h*64 + n*16 + (lane&15)] = f2bf(acc[n][r]*inv);
    }
  }
}

// ---------------- sliding-window attention (window = 65 incl. self) ----------------
__global__ __launch_bounds__(256) void k_window(const u16* __restrict__ q, int ldq,
    const u16* __restrict__ kvwin, int ldkv, u16* __restrict__ comb){
  const int LQ = 72, LV = 136;
  __shared__ u16 q_s [64*LQ];
  __shared__ u16 k_s [128*LQ];
  __shared__ u16 vT_s[64*LV];
  __shared__ u16 p_s [64*LV];
  int bh = blockIdx.x, b = bh>>4, h = bh&15;
  int t0 = blockIdx.y*64;
  int tid = threadIdx.x, lane = tid&63, wid = tid>>6;
  int j0 = t0 - 64;
  bf16x8 zv = {0,0,0,0,0,0,0,0};
  for (int cc=tid; cc<512; cc+=256){
    int r = cc>>3, c8 = cc&7;
    *(bf16x8*)(q_s + r*LQ + c8*8) =
      *(const bf16x8*)(q + (size_t)(b*TSEQ + t0 + r)*ldq + h*HD + c8*8);
  }
  for (int cc=tid; cc<1024; cc+=256){
    int r = cc>>3, c8 = cc&7;
    int j = j0 + r;
    bf16x8 kv8 = (j>=0) ? *(const bf16x8*)(kvwin + (size_t)(b*TSEQ + j)*ldkv + h*HD + c8*8) : zv;
    *(bf16x8*)(k_s + r*LQ + c8*8) = kv8;
    bf16x8 vv8 = (j>=0) ? *(const bf16x8*)(kvwin + (size_t)(b*TSEQ + j)*ldkv + 1024 + h*HD + c8*8) : zv;
    #pragma unroll
    for (int e=0;e<8;e++) vT_s[(c8*8+e)*LV + r] = (u16)vv8[e];
  }
  __syncthreads();
  f32x4 sa[8] = {};
  #pragma unroll
  for (int kk=0;kk<64;kk+=32){
    int lk = kk + ((lane>>4)<<3);
    bf16x8 a = *(const bf16x8*)(q_s + (wid*16 + (lane&15))*LQ + lk);
    #pragma unroll
    for (int n=0;n<8;n++){
      bf16x8 bb = *(const bf16x8*)(k_s + (n*16 + (lane&15))*LQ + lk);
      sa[n] = __builtin_amdgcn_mfma_f32_16x16x32_bf16(a, bb, sa[n], 0,0,0);
    }
  }
  int rl = (lane>>4)<<2;
  float pr[8][4];
  #pragma unroll
  for (int r=0;r<4;r++){
    int ig = t0 + wid*16 + rl + r;
    float mx = -1e30f;
    float sv[8];
    #pragma unroll
    for (int n=0;n<8;n++){
      int jg = j0 + n*16 + (lane&15);
      float s = sa[n][r]*0.125f;
      bool ok = (jg>=0) && (jg<=ig) && (jg>=ig-WIN);
      s = ok ? s : -1e30f;
      sv[n]=s; mx = fmaxf(mx, s);
    }
    #pragma unroll
    for (int m=1;m<16;m<<=1) mx = fmaxf(mx, __shfl_xor(mx, m));
    float sum = 0.f;
    #pragma unroll
    for (int n=0;n<8;n++){ float e = __expf(sv[n]-mx); sv[n]=e; sum += e; }
    #pragma unroll
    for (int m=1;m<16;m<<=1) sum += __shfl_xor(sum, m);
    float inv = 1.0f/sum;
    #pragma unroll
    for (int n=0;n<8;n++) pr[n][r] = sv[n]*inv;
  }
  #pragma unroll
  for (int n=0;n<8;n++)
    #pragma unroll
    for (int r=0;r<4;r++)
      p_s[(wid*16 + rl + r)*LV + n*16 + (lane&15)] = f2bf(pr[n][r]);
  __syncthreads();
  f32x4 oa[4] = {};
  #pragma unroll
  for (int ks=0;ks<4;ks++){
    int lk = ks*32 + ((lane>>4)<<3);
    bf16x8 a = *(const bf16x8*)(p_s + (wid*16 + (lane&15))*LV + lk);
    #pragma unroll
    for (int n=0;n<4;n++){
      bf16x8 bb = *(const bf16x8*)(vT_s + (n*16 + (lane&15))*LV + lk);
      oa[n] = __builtin_amdgcn_mfma_f32_16x16x32_bf16(a, bb, oa[n], 0,0,0);
    }
  }
  #pragma unroll
  for (int n=0;n<4;n++)
    #pragma unroll
    for (int r=0;r<4;r++)
      comb[(size_t)(b*TSEQ + t0 + wid*16 + rl + r)*2048 + 1024 + h*HD + n*16 + (lane&15)]
        = f2bf(oa[n][r]);
}

extern "C" void kernel_launch(void* const* d_in, const int* in_sizes, int n_in,
                              void* d_out, int out_size, void* d_ws, size_t ws_size,
                              hipStream_t stream){
  (void)in_sizes; (void)n_in; (void)out_size; (void)ws_size;
  const float* x    = (const float*)d_in[0];
  const float* enc  = (const float*)d_in[1];
  const float* nw   = (const float*)d_in[2];
  const float* Wq   = (const float*)d_in[3];
  const float* Wkv  = (const float*)d_in[4];
  const float* Wqf  = (const float*)d_in[5];
  const float* Wkf  = (const float*)d_in[6];
  const float* Wwin = (const float*)d_in[7];
  const float* Wout = (const float*)d_in[8];
  float* out = (float*)d_out;

  char* p = (char*)d_ws;
  auto alloc = [&](size_t bytes)->char*{
    char* r = p; p += (bytes + 255) & ~(size_t)255; return r;
  };
  // part (13.1 MB f32) aliases [xn, encb] (16.8 MB) — both dead before k_kvstate.
  char*  aliasBase = p;
  u16*   xn    = (u16*)  alloc((size_t)ROWS*DM*2);
  u16*   encb  = (u16*)  alloc((size_t)ROWS*DM*2);
  u16*   WqwT  = (u16*)  alloc((size_t)3072*DM*2);   // rows 0..1023 Wq^T, 1024..3071 Wwin^T
  u16*   WkvT  = (u16*)  alloc((size_t)2048*DM*2);
  float* part  = (float*)aliasBase;
  u16*   WoutT = (u16*)  alloc((size_t)DM*2048*2);
  u16*   WqfT  = (u16*)  alloc((size_t)FD*HD*2);
  u16*   WkfT  = (u16*)  alloc((size_t)FD*HD*2);
  u16*   qwin  = (u16*)  alloc((size_t)ROWS*3072*2); // [q | k_win | v_win], ld 3072
  u16*   kvb   = (u16*)  alloc((size_t)ROWS*2048*2);
  u16*   kvsT  = (u16*)  alloc((size_t)32*80*FPAD*2);
  u16*   comb  = (u16*)  alloc((size_t)ROWS*2048*2);

  k_prep<<<2*ROWS + 7170, 256, 0, stream>>>(x, enc, nw, Wq, Wwin, Wkv, Wout, Wqf, Wkf,
                                            xn, encb, WqwT, WkvT, WoutT, WqfT, WkfT);

  k_gemm<0><<<dim3(ROWS/128, 40), 512, 0, stream>>>(
      xn, WqwT, qwin, 3072,  encb, WkvT, kvb, 2048,  24, DM, nullptr, nullptr);

  k_kvstate<<<dim3(32, KSPLIT), 256, 0, stream>>>(kvb, WkfT, part);
  k_kvreduce<<<1600, 256, 0, stream>>>(part, kvsT);

  k_linattn<<<dim3(32, TSEQ/64), 256, 0, stream>>>(qwin, WqfT, kvsT, comb);
  k_window <<<dim3(32, TSEQ/64), 256, 0, stream>>>(qwin, 3072, qwin + 1024, 3072, comb);

  k_gemm<1><<<dim3(ROWS/128, 8), 512, 0, stream>>>(
      comb, WoutT, nullptr, DM,  nullptr, nullptr, nullptr, 0,  8, 2048, out, x);
}

// Round 7
// 159.934 us; speedup vs baseline: 2.3590x; 1.0178x over previous
//
#include <hip/hip_runtime.h>

#define DM 1024
#define NH 16
#define HD 64
#define FD 16
#define NF 153
#define FPAD 160
#define WIN 64
#define TSEQ 2048
#define ROWS 4096
#define KSPLIT 8
#define RS2 0.70710678118654752f

typedef unsigned short u16;
typedef __attribute__((ext_vector_type(8))) short bf16x8;
typedef __attribute__((ext_vector_type(8))) unsigned short u16x8;
typedef __attribute__((ext_vector_type(4))) unsigned short u16x4;
typedef __attribute__((ext_vector_type(4))) float f32x4;

#define GLB_AS __attribute__((address_space(1)))
#define LDS_AS __attribute__((address_space(3)))

static __device__ __forceinline__ void gload_lds16(const void* g, void* l){
  __builtin_amdgcn_global_load_lds((const GLB_AS void*)g, (LDS_AS void*)l, 16, 0, 0);
}

static __device__ __forceinline__ float bf2f(u16 u){
  unsigned v = ((unsigned)u) << 16;
  return __builtin_bit_cast(float, v);
}
static __device__ __forceinline__ u16 f2bf(float f){
  unsigned u = __builtin_bit_cast(unsigned, f);
  u += 0x7FFFu + ((u >> 16) & 1u);
  return (u16)(u >> 16);
}

// ---------------- prep (rmsnorm + enc cast) AND weight packing, one dispatch ----------------
static __device__ __forceinline__ void tr_tile(const float* __restrict__ in,
    u16* __restrict__ out, int K, int N, int n0, int k0, float* t, int tid){
  int tx = tid & 31, ty = tid >> 5;
  #pragma unroll
  for (int i=0;i<4;i++) t[(ty + i*8)*33 + tx] = in[(size_t)(k0 + ty + i*8)*N + n0 + tx];
  __syncthreads();
  #pragma unroll
  for (int i=0;i<4;i++) out[(size_t)(n0 + ty + i*8)*K + k0 + tx] = f2bf(t[tx*33 + ty + i*8]);
}

__global__ __launch_bounds__(256) void k_prep(const float* __restrict__ x,
    const float* __restrict__ enc, const float* __restrict__ w,
    const float* __restrict__ Wq, const float* __restrict__ Wwin,
    const float* __restrict__ Wkv, const float* __restrict__ Wout,
    const float* __restrict__ Wqf, const float* __restrict__ Wkf,
    u16* __restrict__ xn, u16* __restrict__ encb,
    u16* __restrict__ WqwT, u16* __restrict__ WkvT, u16* __restrict__ WoutT,
    u16* __restrict__ WqfT, u16* __restrict__ WkfT){
  __shared__ float t[32*33];
  int bx = blockIdx.x, tid = threadIdx.x;
  if (bx < ROWS){
    int row = bx;
    const float4* xr = (const float4*)(x + (size_t)row*DM);
    float4 a = xr[tid];
    float ss = a.x*a.x + a.y*a.y + a.z*a.z + a.w*a.w;
    #pragma unroll
    for (int m=1;m<64;m<<=1) ss += __shfl_xor(ss, m);
    __shared__ float red[4];
    if ((tid&63)==0) red[tid>>6] = ss;
    __syncthreads();
    float tot = red[0]+red[1]+red[2]+red[3];
    float rs = rsqrtf(tot*(1.0f/DM) + 1e-6f);
    float4 wv = ((const float4*)w)[tid];
    u16x4 o;
    o[0]=f2bf(a.x*rs*wv.x); o[1]=f2bf(a.y*rs*wv.y);
    o[2]=f2bf(a.z*rs*wv.z); o[3]=f2bf(a.w*rs*wv.w);
    ((u16x4*)(xn + (size_t)row*DM))[tid] = o;
  } else if (bx < 2*ROWS){
    int row = bx - ROWS;
    float4 a = ((const float4*)(enc + (size_t)row*DM))[tid];
    u16x4 o;
    o[0]=f2bf(a.x); o[1]=f2bf(a.y); o[2]=f2bf(a.z); o[3]=f2bf(a.w);
    ((u16x4*)(encb + (size_t)row*DM))[tid] = o;
  } else {
    int b = bx - 2*ROWS;
    if (b < 1024){
      tr_tile(Wq, WqwT, 1024, 1024, (b&31)*32, (b>>5)*32, t, tid);
    } else if (b < 3072){
      int r = b-1024;
      tr_tile(Wwin, WqwT + (size_t)1024*1024, 1024, 2048, (r&63)*32, (r>>6)*32, t, tid);
    } else if (b < 5120){
      int r = b-3072;
      tr_tile(Wkv, WkvT, 1024, 2048, (r&63)*32, (r>>6)*32, t, tid);
    } else if (b < 7168){
      int r = b-5120;
      tr_tile(Wout, WoutT, 2048, 1024, (r&31)*32, (r>>5)*32, t, tid);
    } else {
      const float* src = (b==7168) ? Wqf : Wkf;
      u16* dst = (b==7168) ? WqfT : WkfT;
      for (int i=tid;i<1024;i+=256) dst[i] = f2bf(src[(i&63)*16 + (i>>6)]);
    }
  }
}

// ---------------- batched pipelined GEMM: 512 threads, 8 waves, wave tile 64x32 ----------------
template<int EPI>
__global__ __launch_bounds__(512) void k_gemm(
    const u16* __restrict__ A0, const u16* __restrict__ B0, u16* __restrict__ C0, int ldc0,
    const u16* __restrict__ A1, const u16* __restrict__ B1, u16* __restrict__ C1, int ldc1,
    int split, int K, float* __restrict__ Cf, const float* __restrict__ resid){
  __shared__ u16 As0[128*64];
  __shared__ u16 Bs0[128*64];
  __shared__ u16 As1[128*64];
  __shared__ u16 Bs1[128*64];
  int by = blockIdx.y;
  const u16 *A, *Bt; u16* C; int ldc;
  if (by < split){ A=A0; Bt=B0; C=C0; ldc=ldc0; }
  else { by -= split; A=A1; Bt=B1; C=C1; ldc=ldc1; }
  int row0 = blockIdx.x*128, col0 = by*128;
  int tid = threadIdx.x, lane = tid&63, wid = tid>>6;
  int wm = wid>>2, wn = wid&3;
  int srow = lane>>3;
  int scb  = ((lane&7)*16) ^ (srow<<4);
  f32x4 acc[4][2] = {};

  auto STAGE = [&](u16* Asb, u16* Bsb, int k0){
    #pragma unroll
    for (int i=0;i<2;i++){
      int chunk = wid*2 + i;
      int r = chunk*8 + srow;
      gload_lds16((const char*)(A  + (size_t)(row0+r)*K + k0) + scb, (char*)Asb + chunk*1024);
      gload_lds16((const char*)(Bt + (size_t)(col0+r)*K + k0) + scb, (char*)Bsb + chunk*1024);
    }
  };
  auto COMPUTE = [&](const u16* Asb, const u16* Bsb){
    #pragma unroll
    for (int kk=0;kk<64;kk+=32){
      int bc = 2*(kk + ((lane>>4)<<3));
      bf16x8 af[4], bfm[2];
      #pragma unroll
      for (int m=0;m<4;m++){
        int r = wm*64 + m*16 + (lane&15);
        af[m]  = *(const bf16x8*)((const char*)Asb + r*128 + (bc ^ ((r&7)<<4)));
      }
      #pragma unroll
      for (int n=0;n<2;n++){
        int r = wn*32 + n*16 + (lane&15);
        bfm[n] = *(const bf16x8*)((const char*)Bsb + r*128 + (bc ^ ((r&7)<<4)));
      }
      #pragma unroll
      for (int m=0;m<4;m++)
        #pragma unroll
        for (int n=0;n<2;n++)
          acc[m][n] = __builtin_amdgcn_mfma_f32_16x16x32_bf16(af[m], bfm[n], acc[m][n], 0,0,0);
    }
  };

  int nt = K >> 6;
  STAGE(As0, Bs0, 0);
  for (int t=0; t<nt-2; t+=2){
    STAGE(As1, Bs1, (t+1)*64);
    asm volatile("s_waitcnt vmcnt(4)" ::: "memory");
    __builtin_amdgcn_s_barrier();
    COMPUTE(As0, Bs0);
    __builtin_amdgcn_s_barrier();
    STAGE(As0, Bs0, (t+2)*64);
    asm volatile("s_waitcnt vmcnt(4)" ::: "memory");
    __builtin_amdgcn_s_barrier();
    COMPUTE(As1, Bs1);
    __builtin_amdgcn_s_barrier();
  }
  STAGE(As1, Bs1, (nt-1)*64);
  asm volatile("s_waitcnt vmcnt(4)" ::: "memory");
  __builtin_amdgcn_s_barrier();
  COMPUTE(As0, Bs0);
  asm volatile("s_waitcnt vmcnt(0)" ::: "memory");
  __builtin_amdgcn_s_barrier();
  COMPUTE(As1, Bs1);

  int rl = (lane>>4)<<2;
  #pragma unroll
  for (int m=0;m<4;m++){
    #pragma unroll
    for (int n=0;n<2;n++){
      int gc = col0 + wn*32 + n*16 + (lane&15);
      #pragma unroll
      for (int r=0;r<4;r++){
        size_t gi = (size_t)(row0 + wm*64 + m*16 + rl + r)*ldc + gc;
        if constexpr (EPI) Cf[gi] = acc[m][n][r] + resid[gi];
        else               C[gi]  = f2bf(acc[m][n][r]);
      }
    }
  }
}

// ---------------- 64x128-tile GEMM (for N-narrow / K-long shapes): 256 thr, 4 waves ----------------
// dbuf 48KB LDS -> 3 blocks/CU; grid (M/64, N/128); counted vmcnt(6).
template<int EPI>
__global__ __launch_bounds__(256) void k_gemm64(const u16* __restrict__ A,
    const u16* __restrict__ Bt, u16* __restrict__ C, float* __restrict__ Cf,
    const float* __restrict__ resid, int ldc, int K){
  __shared__ u16 As0[64*64];
  __shared__ u16 Bs0[128*64];
  __shared__ u16 As1[64*64];
  __shared__ u16 Bs1[128*64];
  int row0 = blockIdx.x*64, col0 = blockIdx.y*128;
  int tid = threadIdx.x, lane = tid&63, wid = tid>>6;
  int wm = wid>>1, wn = wid&1;          // wave tile 32x64
  int srow = lane>>3;
  int scb  = ((lane&7)*16) ^ (srow<<4);
  f32x4 acc[2][4] = {};

  auto STAGE = [&](u16* Asb, u16* Bsb, int k0){
    #pragma unroll
    for (int j=0;j<2;j++){
      int c = wid*2 + j;
      int r = c*8 + srow;
      gload_lds16((const char*)(A + (size_t)(row0+r)*K + k0) + scb, (char*)Asb + c*1024);
    }
    #pragma unroll
    for (int j=0;j<4;j++){
      int c = wid*4 + j;
      int r = c*8 + srow;
      gload_lds16((const char*)(Bt + (size_t)(col0+r)*K + k0) + scb, (char*)Bsb + c*1024);
    }
  };
  auto COMPUTE = [&](const u16* Asb, const u16* Bsb){
    #pragma unroll
    for (int kk=0;kk<64;kk+=32){
      int bc = 2*(kk + ((lane>>4)<<3));
      bf16x8 af[2], bfm[4];
      #pragma unroll
      for (int m=0;m<2;m++){
        int r = wm*32 + m*16 + (lane&15);
        af[m]  = *(const bf16x8*)((const char*)Asb + r*128 + (bc ^ ((r&7)<<4)));
      }
      #pragma unroll
      for (int n=0;n<4;n++){
        int r = wn*64 + n*16 + (lane&15);
        bfm[n] = *(const bf16x8*)((const char*)Bsb + r*128 + (bc ^ ((r&7)<<4)));
      }
      #pragma unroll
      for (int m=0;m<2;m++)
        #pragma unroll
        for (int n=0;n<4;n++)
          acc[m][n] = __builtin_amdgcn_mfma_f32_16x16x32_bf16(af[m], bfm[n], acc[m][n], 0,0,0);
    }
  };

  int nt = K >> 6;
  STAGE(As0, Bs0, 0);
  for (int t=0; t<nt-2; t+=2){
    STAGE(As1, Bs1, (t+1)*64);
    asm volatile("s_waitcnt vmcnt(6)" ::: "memory");
    __builtin_amdgcn_s_barrier();
    COMPUTE(As0, Bs0);
    __builtin_amdgcn_s_barrier();
    STAGE(As0, Bs0, (t+2)*64);
    asm volatile("s_waitcnt vmcnt(6)" ::: "memory");
    __builtin_amdgcn_s_barrier();
    COMPUTE(As1, Bs1);
    __builtin_amdgcn_s_barrier();
  }
  STAGE(As1, Bs1, (nt-1)*64);
  asm volatile("s_waitcnt vmcnt(6)" ::: "memory");
  __builtin_amdgcn_s_barrier();
  COMPUTE(As0, Bs0);
  asm volatile("s_waitcnt vmcnt(0)" ::: "memory");
  __builtin_amdgcn_s_barrier();
  COMPUTE(As1, Bs1);

  int rl = (lane>>4)<<2;
  #pragma unroll
  for (int m=0;m<2;m++){
    #pragma unroll
    for (int n=0;n<4;n++){
      int gc = col0 + wn*64 + n*16 + (lane&15);
      #pragma unroll
      for (int r=0;r<4;r++){
        size_t gi = (size_t)(row0 + wm*32 + m*16 + rl + r)*ldc + gc;
        if constexpr (EPI) Cf[gi] = acc[m][n][r] + resid[gi];
        else               C[gi]  = f2bf(acc[m][n][r]);
      }
    }
  }
}

// ---------------- kv_state with FUSED feature map, split-K=8 ----------------
__global__ __launch_bounds__(256) void k_kvstate(const u16* __restrict__ kvb,
    const u16* __restrict__ WkfT, float* __restrict__ part){
  const int P = 76;
  __shared__ u16 kc[64*64];
  __shared__ u16 wb[16*72];
  __shared__ float fL[64*16];
  __shared__ u16 ph[160*P];
  __shared__ u16 vt[80*P];
  int bh = blockIdx.x, b = bh>>4, h = bh&15;
  int ks = blockIdx.y;
  int tid = threadIdx.x, lane = tid&63, w = tid>>6;
  int srow = lane>>3;
  int scb  = ((lane&7)*16) ^ (srow<<4);
  for (int i=tid;i<1024;i+=256) wb[(i>>6)*72 + (i&63)] = WkfT[i];
  for (int i=tid; i<16*P; i+=256){
    int r = 64 + i/P, c = i - (i/P)*P;
    vt[r*P + c] = (r==64) ? (u16)0x3F80 : (u16)0;
  }
  f32x4 acc[5][3] = {};
  for (int c=0;c<4;c++){
    int s0 = ks*256 + c*64;
    __syncthreads();
    #pragma unroll
    for (int i=0;i<2;i++){
      int ch = w + i*4;
      int r = ch*8 + srow;
      gload_lds16((const char*)(kvb + (size_t)(b*TSEQ + s0 + r)*2048 + h*HD) + scb,
                  (char*)kc + ch*1024);
    }
    for (int s = w; s < 64; s += 4)
      vt[lane*P + s] = kvb[(size_t)(b*TSEQ + s0 + s)*2048 + 1024 + h*HD + lane];
    __syncthreads();
    {
      f32x4 fa = {};
      #pragma unroll
      for (int kk=0;kk<2;kk++){
        int bc = 2*(kk*32 + ((lane>>4)<<3));
        int r = w*16 + (lane&15);
        bf16x8 av = *(const bf16x8*)((const char*)kc + r*128 + (bc ^ ((r&7)<<4)));
        bf16x8 bv = *(const bf16x8*)(wb + (lane&15)*72 + kk*32 + ((lane>>4)<<3));
        fa = __builtin_amdgcn_mfma_f32_16x16x32_bf16(av, bv, fa, 0,0,0);
      }
      int rl = (lane>>4)<<2;
      #pragma unroll
      for (int r=0;r<4;r++) fL[(w*16 + rl + r)*16 + (lane&15)] = fa[r];
    }
    __syncthreads();
    {
      int r = tid>>2, jq = tid&3;
      float4 v0 = *(const float4*)(fL + r*16 + 0);
      float4 v1 = *(const float4*)(fL + r*16 + 4);
      float4 v2 = *(const float4*)(fL + r*16 + 8);
      float4 v3 = *(const float4*)(fL + r*16 + 12);
      float f[16] = {v0.x,v0.y,v0.z,v0.w, v1.x,v1.y,v1.z,v1.w,
                     v2.x,v2.y,v2.z,v2.w, v3.x,v3.y,v3.z,v3.w};
      if ((0&3)==jq) ph[0*P + r] = 0x3F80;
      #pragma unroll
      for (int q=0;q<16;q++) if (((1+q)&3)==jq) ph[(1+q)*P + r] = f2bf(f[q]);
      int pos = 17;
      #pragma unroll
      for (int i=0;i<16;i++)
        #pragma unroll
        for (int j=i;j<16;j++){
          if ((pos&3)==jq) ph[pos*P + r] = f2bf(f[i]*f[j]*((i==j)?0.5f:RS2));
          pos++;
        }
      #pragma unroll
      for (int z=153;z<160;z++) if ((z&3)==jq) ph[z*P + r] = 0;
    }
    __syncthreads();
    #pragma unroll
    for (int kk=0;kk<2;kk++){
      int lk = kk*32 + ((lane>>4)<<3);
      bf16x8 bfr[3];
      #pragma unroll
      for (int nn=0;nn<3;nn++){
        int ncol = (nn<2) ? (w*2+nn) : (8+(w&1));
        bfr[nn] = *(const bf16x8*)(ph + (ncol*16 + (lane&15))*P + lk);
      }
      #pragma unroll
      for (int m=0;m<5;m++){
        bf16x8 av = *(const bf16x8*)(vt + (m*16 + (lane&15))*P + lk);
        #pragma unroll
        for (int nn=0;nn<3;nn++)
          acc[m][nn] = __builtin_amdgcn_mfma_f32_16x16x32_bf16(av, bfr[nn], acc[m][nn], 0,0,0);
      }
    }
  }
  int rl = (lane>>4)<<2;
  float* pp = part + ((size_t)ks*32 + bh)*80*160;
  #pragma unroll
  for (int m=0;m<5;m++){
    #pragma unroll
    for (int nn=0;nn<3;nn++){
      int ncol = (nn<2) ? (w*2+nn) : (8+(w&1));
      if (nn==2 && w>=2) continue;
      int fcol = ncol*16 + (lane&15);
      #pragma unroll
      for (int r=0;r<4;r++)
        pp[(size_t)(m*16 + rl + r)*160 + fcol] = acc[m][nn][r];
    }
  }
}

// ---------------- reduce split-K partials -> kvsT bf16 [bh][80][160] ----------------
__global__ __launch_bounds__(256) void k_kvreduce(const float* __restrict__ part,
    u16* __restrict__ kvsT){
  int i = blockIdx.x*256 + threadIdx.x;
  float s = 0.f;
  #pragma unroll
  for (int c=0;c<KSPLIT;c++) s += part[(size_t)c*409600 + i];
  kvsT[i] = f2bf(s);
}

// ---------------- FUSED linear-attention + sliding-window attention ----------------
// One 64-row q-tile per block; q staged ONCE (gload_lds swizzled) and used by both
// the feature-map MFMA and the window QK^T. LDS union: linattn set {fL,As,Bs}
// overlaid by window set {k_s,vT,p_s} (phase-disjoint, barrier-separated). 63.7KB.
__global__ __launch_bounds__(256) void k_attn(const u16* __restrict__ qwin,
    const u16* __restrict__ WqfT, const u16* __restrict__ kvsT, u16* __restrict__ comb){
  const int LS = 168, LQ = 72, LV = 136;
  __shared__ u16 arena[4096 + 1152 + 26624];
  u16*   qc  = arena;                 // [64][64] swizzled (128B rows)
  u16*   wb  = arena + 4096;          // [16][72]
  u16*   uni = arena + 5248;
  float* fL  = (float*)uni;           // [64][16]
  u16*   As  = uni + 2048;            // [64][LS]
  u16*   Bs  = uni + 12800;           // [80][LS]
  u16*   k_s = uni;                   // [128][LQ]  (window phase)
  u16*   vT  = uni + 9216;            // [64][LV]
  u16*   p_s = uni + 17920;           // [64][LV]

  int bh = blockIdx.x, b = bh>>4, h = bh&15;
  int t0 = blockIdx.y*64;
  int tid = threadIdx.x, lane = tid&63, wid = tid>>6;
  int srow = lane>>3;
  int scb  = ((lane&7)*16) ^ (srow<<4);

  // ---- stage q (once), wb, Bs(kvsT) ----
  #pragma unroll
  for (int i=0;i<2;i++){
    int ch = wid + i*4;
    int r = ch*8 + srow;
    gload_lds16((const char*)(qwin + (size_t)(b*TSEQ + t0 + r)*3072 + h*HD) + scb,
                (char*)qc + ch*1024);
  }
  for (int i=tid;i<1024;i+=256) wb[(i>>6)*72 + (i&63)] = WqfT[i];
  for (int i=tid*8; i<80*FPAD; i+=2048){
    int r = i/FPAD, ff = i - r*FPAD;
    *(bf16x8*)(Bs + r*LS + ff) = *(const bf16x8*)(kvsT + (size_t)bh*80*FPAD + i);
  }
  __syncthreads();

  // ---- feature map MFMA: fL = q_chunk @ Wqf ----
  {
    f32x4 fa = {};
    #pragma unroll
    for (int kk=0;kk<2;kk++){
      int bc = 2*(kk*32 + ((lane>>4)<<3));
      int r = wid*16 + (lane&15);
      bf16x8 av = *(const bf16x8*)((const char*)qc + r*128 + (bc ^ ((r&7)<<4)));
      bf16x8 bv = *(const bf16x8*)(wb + (lane&15)*72 + kk*32 + ((lane>>4)<<3));
      fa = __builtin_amdgcn_mfma_f32_16x16x32_bf16(av, bv, fa, 0,0,0);
    }
    int rl = (lane>>4)<<2;
    #pragma unroll
    for (int r=0;r<4;r++) fL[(wid*16 + rl + r)*16 + (lane&15)] = fa[r];
  }
  __syncthreads();

  // ---- triu expansion -> As (phi rows) ----
  {
    int r = tid>>2, jq = tid&3;
    float4 v0 = *(const float4*)(fL + r*16 + 0);
    float4 v1 = *(const float4*)(fL + r*16 + 4);
    float4 v2 = *(const float4*)(fL + r*16 + 8);
    float4 v3 = *(const float4*)(fL + r*16 + 12);
    float f[16] = {v0.x,v0.y,v0.z,v0.w, v1.x,v1.y,v1.z,v1.w,
                   v2.x,v2.y,v2.z,v2.w, v3.x,v3.y,v3.z,v3.w};
    if ((0&3)==jq) As[r*LS + 0] = 0x3F80;
    #pragma unroll
    for (int q=0;q<16;q++) if (((1+q)&3)==jq) As[r*LS + 1+q] = f2bf(f[q]);
    int pos = 17;
    #pragma unroll
    for (int i=0;i<16;i++)
      #pragma unroll
      for (int j=i;j<16;j++){
        if ((pos&3)==jq) As[r*LS + pos] = f2bf(f[i]*f[j]*((i==j)?0.5f:RS2));
        pos++;
      }
    #pragma unroll
    for (int z=153;z<160;z++) if ((z&3)==jq) As[r*LS + z] = 0;
  }
  __syncthreads();

  // ---- linear attention MFMA + normalize + write lin half ----
  {
    f32x4 acc[5] = {};
    #pragma unroll
    for (int ks=0;ks<5;ks++){
      int lk = ks*32 + ((lane>>4)<<3);
      bf16x8 a = *(const bf16x8*)(As + (wid*16 + (lane&15))*LS + lk);
      #pragma unroll
      for (int n=0;n<5;n++){
        bf16x8 bb = *(const bf16x8*)(Bs + (n*16 + (lane&15))*LS + lk);
        acc[n] = __builtin_amdgcn_mfma_f32_16x16x32_bf16(a, bb, acc[n], 0,0,0);
      }
    }
    int rl = (lane>>4)<<2;
    #pragma unroll
    for (int r=0;r<4;r++){
      float nrm = __shfl(acc[4][r], lane & 48) + 1e-6f;
      float inv = 1.0f / nrm;
      int t = t0 + wid*16 + rl + r;
      #pragma unroll
      for (int n=0;n<4;n++){
        comb[(size_t)(b*TSEQ + t)*2048 + h*64 + n*16 + (lane&15)] = f2bf(acc[n][r]*inv);
      }
    }
  }
  __syncthreads();   // all As/Bs reads done -> union region may be overwritten

  // ---- stage window K and V^T (rows j0..j0+127 / j0..j0+63+64) ----
  int j0 = t0 - 64;
  bf16x8 zv = {0,0,0,0,0,0,0,0};
  for (int cc=tid; cc<1024; cc+=256){
    int r = cc>>3, c8 = cc&7;
    int j = j0 + r;
    bf16x8 kv8 = (j>=0) ? *(const bf16x8*)(qwin + (size_t)(b*TSEQ + j)*3072 + 1024 + h*HD + c8*8) : zv;
    *(bf16x8*)(k_s + r*LQ + c8*8) = kv8;
    bf16x8 vv8 = (j>=0) ? *(const bf16x8*)(qwin + (size_t)(b*TSEQ + j)*3072 + 2048 + h*HD + c8*8) : zv;
    #pragma unroll
    for (int e=0;e<8;e++) vT[(c8*8+e)*LV + r] = (u16)vv8[e];
  }
  __syncthreads();

  // ---- QK^T (A from qc), mask, softmax, p_s ----
  f32x4 sa[8] = {};
  #pragma unroll
  for (int kk=0;kk<64;kk+=32){
    int bc = 2*(kk + ((lane>>4)<<3));
    int rq = wid*16 + (lane&15);
    bf16x8 a = *(const bf16x8*)((const char*)qc + rq*128 + (bc ^ ((rq&7)<<4)));
    int lk = kk + ((lane>>4)<<3);
    #pragma unroll
    for (int n=0;n<8;n++){
      bf16x8 bb = *(const bf16x8*)(k_s + (n*16 + (lane&15))*LQ + lk);
      sa[n] = __builtin_amdgcn_mfma_f32_16x16x32_bf16(a, bb, sa[n], 0,0,0);
    }
  }
  int rl = (lane>>4)<<2;
  float pr[8][4];
  #pragma unroll
  for (int r=0;r<4;r++){
    int ig = t0 + wid*16 + rl + r;
    float mx = -1e30f;
    float sv[8];
    #pragma unroll
    for (int n=0;n<8;n++){
      int jg = j0 + n*16 + (lane&15);
      float s = sa[n][r]*0.125f;
      bool ok = (jg>=0) && (jg<=ig) && (jg>=ig-WIN);
      s = ok ? s : -1e30f;
      sv[n]=s; mx = fmaxf(mx, s);
    }
    #pragma unroll
    for (int m=1;m<16;m<<=1) mx = fmaxf(mx, __shfl_xor(mx, m));
    float sum = 0.f;
    #pragma unroll
    for (int n=0;n<8;n++){ float e = __expf(sv[n]-mx); sv[n]=e; sum += e; }
    #pragma unroll
    for (int m=1;m<16;m<<=1) sum += __shfl_xor(sum, m);
    float inv = 1.0f/sum;
    #pragma unroll
    for (int n=0;n<8;n++) pr[n][r] = sv[n]*inv;
  }
  #pragma unroll
  for (int n=0;n<8;n++)
    #pragma unroll
    for (int r=0;r<4;r++)
      p_s[(wid*16 + rl + r)*LV + n*16 + (lane&15)] = f2bf(pr[n][r]);
  __syncthreads();

  // ---- PV ----
  f32x4 oa[4] = {};
  #pragma unroll
  for (int ks=0;ks<4;ks++){
    int lk = ks*32 + ((lane>>4)<<3);
    bf16x8 a = *(const bf16x8*)(p_s + (wid*16 + (lane&15))*LV + lk);
    #pragma unroll
    for (int n=0;n<4;n++){
      bf16x8 bb = *(const bf16x8*)(vT + (n*16 + (lane&15))*LV + lk);
      oa[n] = __builtin_amdgcn_mfma_f32_16x16x32_bf16(a, bb, oa[n], 0,0,0);
    }
  }
  #pragma unroll
  for (int n=0;n<4;n++)
    #pragma unroll
    for (int r=0;r<4;r++)
      comb[(size_t)(b*TSEQ + t0 + wid*16 + rl + r)*2048 + 1024 + h*HD + n*16 + (lane&15)]
        = f2bf(oa[n][r]);
}

extern "C" void kernel_launch(void* const* d_in, const int* in_sizes, int n_in,
                              void* d_out, int out_size, void* d_ws, size_t ws_size,
                              hipStream_t stream){
  (void)in_sizes; (void)n_in; (void)out_size; (void)ws_size;
  const float* x    = (const float*)d_in[0];
  const float* enc  = (const float*)d_in[1];
  const float* nw   = (const float*)d_in[2];
  const float* Wq   = (const float*)d_in[3];
  const float* Wkv  = (const float*)d_in[4];
  const float* Wqf  = (const float*)d_in[5];
  const float* Wkf  = (const float*)d_in[6];
  const float* Wwin = (const float*)d_in[7];
  const float* Wout = (const float*)d_in[8];
  float* out = (float*)d_out;

  char* p = (char*)d_ws;
  auto alloc = [&](size_t bytes)->char*{
    char* r = p; p += (bytes + 255) & ~(size_t)255; return r;
  };
  // part (13.1 MB f32) aliases [xn, encb] (16.8 MB) — both dead before k_kvstate.
  char*  aliasBase = p;
  u16*   xn    = (u16*)  alloc((size_t)ROWS*DM*2);
  u16*   encb  = (u16*)  alloc((size_t)ROWS*DM*2);
  u16*   WqwT  = (u16*)  alloc((size_t)3072*DM*2);   // rows 0..1023 Wq^T, 1024..3071 Wwin^T
  u16*   WkvT  = (u16*)  alloc((size_t)2048*DM*2);
  float* part  = (float*)aliasBase;
  u16*   WoutT = (u16*)  alloc((size_t)DM*2048*2);
  u16*   WqfT  = (u16*)  alloc((size_t)FD*HD*2);
  u16*   WkfT  = (u16*)  alloc((size_t)FD*HD*2);
  u16*   qwin  = (u16*)  alloc((size_t)ROWS*3072*2); // [q | k_win | v_win], ld 3072
  u16*   kvb   = (u16*)  alloc((size_t)ROWS*2048*2);
  u16*   kvsT  = (u16*)  alloc((size_t)32*80*FPAD*2);
  u16*   comb  = (u16*)  alloc((size_t)ROWS*2048*2);

  k_prep<<<2*ROWS + 7170, 256, 0, stream>>>(x, enc, nw, Wq, Wwin, Wkv, Wout, Wqf, Wkf,
                                            xn, encb, WqwT, WkvT, WoutT, WqfT, WkfT);

  k_gemm<0><<<dim3(ROWS/128, 40), 512, 0, stream>>>(
      xn, WqwT, qwin, 3072,  encb, WkvT, kvb, 2048,  24, DM, nullptr, nullptr);

  k_kvstate<<<dim3(32, KSPLIT), 256, 0, stream>>>(kvb, WkfT, part);
  k_kvreduce<<<1600, 256, 0, stream>>>(part, kvsT);

  k_attn<<<dim3(32, TSEQ/64), 256, 0, stream>>>(qwin, WqfT, kvsT, comb);

  k_gemm64<1><<<dim3(ROWS/64, 8), 256, 0, stream>>>(
      comb, WoutT, nullptr, out, x, DM, 2048);
}